// Round 6
// baseline (2186.610 us; speedup 1.0000x reference)
//
#include <hip/hip_runtime.h>
#include <hip/hip_bf16.h>

#define DI __device__ __forceinline__

typedef unsigned short u16;
typedef unsigned int   u32;
typedef float  f32x4  __attribute__((ext_vector_type(4)));
typedef __bf16 bf16x8 __attribute__((ext_vector_type(8)));
typedef u16    us8    __attribute__((ext_vector_type(8)));

DI u16 f2bf(float f){
  u32 u = __builtin_bit_cast(u32, f);
  u = (u + 0x7fffu + ((u >> 16) & 1u)) >> 16;
  return (u16)u;
}

DI f32x4 mfma16(bf16x8 a, bf16x8 b, f32x4 c){
  return __builtin_amdgcn_mfma_f32_16x16x32_bf16(a, b, c, 0, 0, 0);
}
DI bf16x8 bzero(){
  us8 z = {0,0,0,0,0,0,0,0};
  return __builtin_bit_cast(bf16x8, z);
}
DI bf16x8 ld8s(const u16* p){ return *(const bf16x8*)p; }

// ---------------------------------------------------------------------------
// Kernel 0: weight prep — bf16 transposed copies + rel-pos bias table
//           TRANSPOSED: biasT[h][key][query]
// ---------------------------------------------------------------------------
__global__ void prep_kernel(const float* __restrict__ qkv_w, const float* __restrict__ proj_w,
                            const float* __restrict__ w1,    const float* __restrict__ w2,
                            const float* __restrict__ rpb,
                            u16* __restrict__ qkvwT, u16* __restrict__ projwT,
                            u16* __restrict__ w1T,   u16* __restrict__ w2T,
                            float* __restrict__ biasT)
{
  const int idx = blockIdx.x * blockDim.x + threadIdx.x;
  const int stride = gridDim.x * blockDim.x;
  for (int i = idx; i < 384*128; i += stride){ int o = i >> 7, k = i & 127; qkvwT[i] = f2bf(qkv_w[k*384 + o]); }
  for (int i = idx; i < 128*128; i += stride){ int o = i >> 7, k = i & 127; projwT[i] = f2bf(proj_w[k*128 + o]); }
  for (int i = idx; i < 512*128; i += stride){ int o = i >> 7, k = i & 127; w1T[i] = f2bf(w1[k*512 + o]); }
  for (int i = idx; i < 128*512; i += stride){ int o = i >> 9, k = i & 511; w2T[i] = f2bf(w2[k*128 + o]); }
  // biasT[h*2401 + key*49 + query] = rpb[REL_IDX[query][key]*8 + h]
  for (int i = idx; i < 8*49*49; i += stride){
    int h = i / 2401, rem = i % 2401, a = rem / 49, b = rem % 49; // a=key, b=query
    int rel = (b/7 - a/7 + 6) * 13 + (b%7 - a%7 + 6);
    biasT[i] = rpb[rel*8 + h];
  }
}

// ---------------------------------------------------------------------------
// Kernel 1: one block = one 7x7 window. LN1 + shift-gather + QKV(MFMA) +
//           fused MFMA attention+proj (S^T trick; P and O^T both kept in
//           registers via shfl-repack; no LDS after QKV scatter) + residual.
// ---------------------------------------------------------------------------
__global__ __launch_bounds__(256, 3) void attn_kernel(
    const float* __restrict__ x,
    const float* __restrict__ ln1w, const float* __restrict__ ln1b,
    const float* __restrict__ qkv_b, const float* __restrict__ proj_b,
    const u16* __restrict__ qkvwT, const u16* __restrict__ projwT,
    const float* __restrict__ biasT,
    float* __restrict__ y)
{
  __shared__ u16 qB[64*136];     // q*scale bf16 [tok][ch], padded stride 136
  __shared__ u16 kB[64*136];     // k bf16 [tok][ch], padded stride 136
  __shared__ u16 pool[128*72];   // phase A: xn bf16 [64][128] swizzled; phase B: vT [ch][tok] stride 72
  __shared__ float mu_s[64], rs_s[64];
  __shared__ int lab_s[64];

  u16* xw = pool;

  const int tid = threadIdx.x;
  const int lane = tid & 63;
  const int wv = tid >> 6;       // wave 0..3
  const int l15 = lane & 15;
  const int lq  = lane >> 4;     // 0..3
  const int blk = blockIdx.x;
  const int b  = blk >> 8;
  const int wi = blk & 255;
  const int wh = wi >> 4, ww = wi & 15;

  // ---- Stage 1: gather (roll -3,-3) + LN1 -> xw (bf16, swizzled), stats ----
  {
    const int t = tid >> 2;     // token 0..63
    const int g = tid & 3;      // channel quarter
    float vals[32];
    float sum = 0.f, sq = 0.f;
    if (t < 49){
      const int r = t / 7, c = t % 7;
      const int hs   = (wh*7 + r + 3) % 112;
      const int wsrc = (ww*7 + c + 3) % 112;
      const float* src = x + ((size_t)((b*112 + hs)*112 + wsrc))*128 + g*32;
      #pragma unroll
      for (int j = 0; j < 8; j++){
        float4 v4 = *(const float4*)(src + 4*j);
        vals[4*j+0]=v4.x; vals[4*j+1]=v4.y; vals[4*j+2]=v4.z; vals[4*j+3]=v4.w;
        sum += v4.x + v4.y + v4.z + v4.w;
        sq  += v4.x*v4.x + v4.y*v4.y + v4.z*v4.z + v4.w*v4.w;
      }
    }
    sum += __shfl_xor(sum, 1); sum += __shfl_xor(sum, 2);
    sq  += __shfl_xor(sq, 1);  sq  += __shfl_xor(sq, 2);
    const float mu = sum * (1.f/128.f);
    const float var = sq * (1.f/128.f) - mu*mu;
    const float rs = rsqrtf(var + 1e-5f);
    if (g == 0){
      mu_s[t] = mu; rs_s[t] = rs;
      const int r = t / 7, c = t % 7;
      const int rh = (wh == 15) ? ((r < 4) ? 1 : 2) : 0;
      const int rw = (ww == 15) ? ((c < 4) ? 1 : 2) : 0;
      lab_s[t] = rh*3 + rw;
    }
    #pragma unroll
    for (int j = 0; j < 32; j++){
      const int ch = g*32 + j;
      float xn = 0.f;
      if (t < 49) xn = (vals[j] - mu) * rs * ln1w[ch] + ln1b[ch];
      xw[(t*128 + ch) ^ ((t & 7) << 3)] = f2bf(xn);
    }
  }
  __syncthreads();

  // ---- Stage 2: QKV GEMM [64x128]@[128x384] -> qB/kB/pool-vT ----
  {
    const f32x4 fz = {0.f,0.f,0.f,0.f};
    f32x4 acc[4][6];
    #pragma unroll
    for (int mt = 0; mt < 4; mt++)
      #pragma unroll
      for (int nt = 0; nt < 6; nt++) acc[mt][nt] = fz;

    const int col0 = wv * 96;
    #pragma unroll
    for (int kk = 0; kk < 4; kk++){
      const int k0 = kk*32 + (lq << 3);
      bf16x8 a[4];
      #pragma unroll
      for (int mt = 0; mt < 4; mt++){
        const int row = mt*16 + l15;
        a[mt] = ld8s(&xw[(row*128 + k0) ^ ((row & 7) << 3)]);
      }
      #pragma unroll
      for (int nt = 0; nt < 6; nt++){
        const int o = col0 + nt*16 + l15;
        const bf16x8 bb = *(const bf16x8*)(qkvwT + o*128 + k0);
        #pragma unroll
        for (int mt = 0; mt < 4; mt++)
          acc[mt][nt] = mfma16(a[mt], bb, acc[mt][nt]);
      }
    }
    __syncthreads();   // all xw reads done before vT overwrites pool
    #pragma unroll
    for (int nt = 0; nt < 6; nt++){
      const int o = col0 + nt*16 + l15;
      const int which = o >> 7;          // 0:q 1:k 2:v
      const int ch = o & 127;
      const float bias = qkv_b[o];
      #pragma unroll
      for (int mt = 0; mt < 4; mt++){
        #pragma unroll
        for (int r = 0; r < 4; r++){
          const int tok = mt*16 + (lq << 2) + r;
          const float v = acc[mt][nt][r] + bias;
          if (which == 0)      qB[tok*136 + ch] = f2bf(v * 0.25f);
          else if (which == 1) kB[tok*136 + ch] = f2bf(v);
          else                 pool[ch*72 + tok] = f2bf(v);
        }
      }
    }
  }
  __syncthreads();

  // ---- Stage 3+4 fused: S^T = mfma(K,Q); softmax across lq lanes;
  //      P -> B-frag repack; O^T = mfma(V^T, P^T); O^T -> A-frag repack;
  //      proj accumulated per 4-head batch. No LDS, no barriers. ----
  const f32x4 fz = {0.f,0.f,0.f,0.f};
  f32x4 acc4[8];
  #pragma unroll
  for (int nt = 0; nt < 8; nt++) acc4[nt] = fz;
  {
    const int iq = wv*16 + l15;            // this lane's query token
    const int labq = lab_s[iq];
    float mterm[4][4];
    #pragma unroll
    for (int nt = 0; nt < 4; nt++)
      #pragma unroll
      for (int r = 0; r < 4; r++){
        const int jk = nt*16 + (lq << 2) + r;   // key token
        float mv = 0.f;
        if (jk >= 49) mv = -1e30f;
        else if (iq < 49 && labq != lab_s[jk]) mv = -100.f;
        mterm[nt][r] = mv;
      }
    #pragma unroll 1
    for (int hb = 0; hb < 2; hb++){
      // --- S for 4 heads ---
      float p[4][4][4];
      #pragma unroll
      for (int hh = 0; hh < 4; hh++){
        const int h = hb*4 + hh;
        const bf16x8 bq = (lq < 2) ? ld8s(&qB[iq*136 + h*16 + (lq << 3)]) : bzero();
        #pragma unroll
        for (int nt = 0; nt < 4; nt++){
          const bf16x8 ak = (lq < 2) ? ld8s(&kB[(nt*16 + l15)*136 + h*16 + (lq << 3)]) : bzero();
          const f32x4 s4 = mfma16(ak, bq, fz);   // D[key][query]
          #pragma unroll
          for (int r = 0; r < 4; r++){
            const int jk = nt*16 + (lq << 2) + r;
            float s = s4[r] + mterm[nt][r];
            if (jk < 49 && iq < 49) s += biasT[h*2401 + jk*49 + iq];
            p[hh][nt][r] = s;
          }
        }
      }
      // --- softmax, 4 independent chains (keys distributed over regs x lq) ---
      #pragma unroll
      for (int hh = 0; hh < 4; hh++){
        float m = -3e38f;
        #pragma unroll
        for (int nt = 0; nt < 4; nt++)
          #pragma unroll
          for (int r = 0; r < 4; r++) m = fmaxf(m, p[hh][nt][r]);
        m = fmaxf(m, __shfl_xor(m, 16));
        m = fmaxf(m, __shfl_xor(m, 32));
        float sum = 0.f;
        #pragma unroll
        for (int nt = 0; nt < 4; nt++)
          #pragma unroll
          for (int r = 0; r < 4; r++){
            const float e = __expf(p[hh][nt][r] - m);
            p[hh][nt][r] = e;
            sum += e;
          }
        sum += __shfl_xor(sum, 16);
        sum += __shfl_xor(sum, 32);
        const float inv = 1.f / sum;
        #pragma unroll
        for (int nt = 0; nt < 4; nt++)
          #pragma unroll
          for (int r = 0; r < 4; r++) p[hh][nt][r] *= inv;
      }
      // --- PV as O^T = mfma(A=V^T, B=P^T): oT[hh][r] = AO[wv*16+l15][h*16+lq*4+r] ---
      f32x4 oT[4];
      #pragma unroll
      for (int hh = 0; hh < 4; hh++) oT[hh] = fz;
      #pragma unroll
      for (int hh = 0; hh < 4; hh++){
        const int h = hb*4 + hh;
        #pragma unroll
        for (int kk = 0; kk < 2; kk++){
          us8 tmp;
          #pragma unroll
          for (int j = 0; j < 8; j++){
            const int srcLane = ((((lq << 1) + (j >> 2)) & 3) << 4) + l15;
            const float va = __shfl(p[hh][2*kk    ][j & 3], srcLane);
            const float vb = __shfl(p[hh][2*kk + 1][j & 3], srcLane);
            tmp[j] = f2bf((lq & 2) ? vb : va);
          }
          const bf16x8 pb = __builtin_bit_cast(bf16x8, tmp);
          const bf16x8 av = ld8s(&pool[(h*16 + l15)*72 + kk*32 + (lq << 3)]);
          oT[hh] = mfma16(av, pb, oT[hh]);
        }
      }
      // --- proj partial: ao A-frags from oT via same repack; K-chunks of this half ---
      #pragma unroll
      for (int kkl = 0; kkl < 2; kkl++){
        us8 tmp;
        #pragma unroll
        for (int j = 0; j < 8; j++){
          const int srcLane = ((((lq << 1) + (j >> 2)) & 3) << 4) + l15;
          const float va = __shfl(oT[2*kkl    ][j & 3], srcLane);
          const float vb = __shfl(oT[2*kkl + 1][j & 3], srcLane);
          tmp[j] = f2bf((lq & 2) ? vb : va);
        }
        const bf16x8 a4 = __builtin_bit_cast(bf16x8, tmp);
        const int k0 = hb*64 + kkl*32 + (lq << 3);
        #pragma unroll
        for (int nt = 0; nt < 8; nt++){
          const bf16x8 bb = *(const bf16x8*)(projwT + (nt*16 + l15)*128 + k0);
          acc4[nt] = mfma16(a4, bb, acc4[nt]);
        }
      }
    }
  }

  // ---- Epilogue: residual write for this wave's 16 tokens ----
  {
    #pragma unroll
    for (int nt = 0; nt < 8; nt++){
      const int ch = nt*16 + l15;
      const float pb = proj_b[ch];
      const float lw = ln1w[ch], lb = ln1b[ch];
      #pragma unroll
      for (int r = 0; r < 4; r++){
        const int tok = wv*16 + (lq << 2) + r;
        if (tok < 49){
          const int rr = tok / 7, cc = tok % 7;
          const int hs   = (wh*7 + rr + 3) % 112;
          const int wsrc = (ww*7 + cc + 3) % 112;
          const size_t gi = ((size_t)((b*112 + hs)*112 + wsrc))*128 + ch;
          const float xn = (x[gi] - mu_s[tok]) * rs_s[tok] * lw + lb;
          y[gi] = xn + acc4[nt][r] + pb;
        }
      }
    }
  }
}

// ---------------------------------------------------------------------------
// Kernel 2: MLP, 4 x 64-token tiles per block (weight-traffic amortization),
// original y cached in LDS (yf), epilogue accumulated in LDS and written back
// with coalesced float4 stores.
// ---------------------------------------------------------------------------
__global__ __launch_bounds__(256, 2) void mlp_kernel(
    const float* __restrict__ ln2w, const float* __restrict__ ln2b,
    const float* __restrict__ b1, const float* __restrict__ b2,
    const u16* __restrict__ w1T, const u16* __restrict__ w2T,
    float* __restrict__ y)
{
  __shared__ u16 yn[64*128];     // 16KB
  __shared__ u16 hid[64*256];    // 32KB (one 256-col half)
  __shared__ float yf[64*128];   // 32KB original y (f32, xor-swizzled by <<2)
  const int tid = threadIdx.x;
  const int lane = tid & 63;
  const int wv = tid >> 6;
  const int l15 = lane & 15;
  const int lq  = lane >> 4;
  const f32x4 fz = {0.f,0.f,0.f,0.f};

  #pragma unroll 1
  for (int tile = 0; tile < 4; ++tile){
    const size_t base = ((size_t)blockIdx.x * 4 + tile) * 64;

    // LN2 -> yn (bf16), y -> yf (f32)
    {
      const int t = tid >> 2, g = tid & 3;
      const float* src = y + (base + t)*128 + g*32;
      float vals[32];
      float sum = 0.f, sq = 0.f;
      #pragma unroll
      for (int j = 0; j < 8; j++){
        float4 v4 = *(const float4*)(src + 4*j);
        vals[4*j+0]=v4.x; vals[4*j+1]=v4.y; vals[4*j+2]=v4.z; vals[4*j+3]=v4.w;
        sum += v4.x + v4.y + v4.z + v4.w;
        sq  += v4.x*v4.x + v4.y*v4.y + v4.z*v4.z + v4.w*v4.w;
      }
      sum += __shfl_xor(sum, 1); sum += __shfl_xor(sum, 2);
      sq  += __shfl_xor(sq, 1);  sq  += __shfl_xor(sq, 2);
      const float mu = sum * (1.f/128.f);
      const float rs = rsqrtf(sq * (1.f/128.f) - mu*mu + 1e-5f);
      #pragma unroll
      for (int j = 0; j < 32; j++){
        const int ch = g*32 + j;
        yf[(t*128 + ch) ^ ((t & 7) << 2)] = vals[j];
        yn[(t*128 + ch) ^ ((t & 7) << 3)] = f2bf((vals[j] - mu) * rs * ln2w[ch] + ln2b[ch]);
      }
    }
    __syncthreads();

    f32x4 acc2[4][2];
    #pragma unroll
    for (int mt = 0; mt < 4; mt++){ acc2[mt][0] = fz; acc2[mt][1] = fz; }

    #pragma unroll 1
    for (int half = 0; half < 2; half++){
      // GEMM1 [64x128]@[128x256] + GELU -> hid
      {
        f32x4 acc[4][4];
        #pragma unroll
        for (int mt = 0; mt < 4; mt++)
          #pragma unroll
          for (int nt = 0; nt < 4; nt++) acc[mt][nt] = fz;
        #pragma unroll
        for (int kk = 0; kk < 4; kk++){
          const int k0 = kk*32 + (lq << 3);
          bf16x8 a[4];
          #pragma unroll
          for (int mt = 0; mt < 4; mt++){
            const int row = mt*16 + l15;
            a[mt] = ld8s(&yn[(row*128 + k0) ^ ((row & 7) << 3)]);
          }
          #pragma unroll
          for (int nt = 0; nt < 4; nt++){
            const int o = half*256 + wv*64 + nt*16 + l15;
            const bf16x8 bb = *(const bf16x8*)(w1T + o*128 + k0);
            #pragma unroll
            for (int mt = 0; mt < 4; mt++)
              acc[mt][nt] = mfma16(a[mt], bb, acc[mt][nt]);
          }
        }
        #pragma unroll
        for (int nt = 0; nt < 4; nt++){
          const int o = half*256 + wv*64 + nt*16 + l15;
          const int cl = o - half*256;           // local col 0..255
          const float bb1 = b1[o];
          #pragma unroll
          for (int mt = 0; mt < 4; mt++){
            #pragma unroll
            for (int r = 0; r < 4; r++){
              const int tok = mt*16 + (lq << 2) + r;
              const float v = acc[mt][nt][r] + bb1;
              const float u = 0.7978845608028654f * (v + 0.044715f * v*v*v);
              const float th = 1.f - 2.f / (__expf(2.f*u) + 1.f);
              const float gel = 0.5f * v * (1.f + th);
              hid[(tok*256 + cl) ^ ((tok & 7) << 3)] = f2bf(gel);
            }
          }
        }
      }
      __syncthreads();

      // GEMM2 partial: [64x256]@[256x128], accumulate acc2
      {
        #pragma unroll
        for (int kk = 0; kk < 8; kk++){
          const int k0 = kk*32 + (lq << 3);      // local k in half: 0..255
          bf16x8 a[4];
          #pragma unroll
          for (int mt = 0; mt < 4; mt++){
            const int row = mt*16 + l15;
            a[mt] = ld8s(&hid[(row*256 + k0) ^ ((row & 7) << 3)]);
          }
          #pragma unroll
          for (int nt = 0; nt < 2; nt++){
            const int o = wv*32 + nt*16 + l15;
            const int kg = half*256 + k0;
            const bf16x8 bb = *(const bf16x8*)(w2T + o*512 + kg);
            #pragma unroll
            for (int mt = 0; mt < 4; mt++)
              acc2[mt][nt] = mfma16(a[mt], bb, acc2[mt][nt]);
          }
        }
      }
      __syncthreads();
    }

    // epilogue: accumulate into yf (each (tok,ch) owned by one thread)
    #pragma unroll
    for (int nt = 0; nt < 2; nt++){
      const int ch = wv*32 + nt*16 + l15;
      const float bb2 = b2[ch];
      #pragma unroll
      for (int mt = 0; mt < 4; mt++){
        #pragma unroll
        for (int r = 0; r < 4; r++){
          const int tok = mt*16 + (lq << 2) + r;
          yf[(tok*128 + ch) ^ ((tok & 7) << 2)] += acc2[mt][nt][r] + bb2;
        }
      }
    }
    __syncthreads();

    // coalesced float4 writeback
    {
      const int t = tid >> 2, g = tid & 3;
      float* dst = y + (base + t)*128 + g*32;
      #pragma unroll
      for (int j = 0; j < 8; j++){
        float4 o4;
        o4.x = yf[(t*128 + g*32 + 4*j + 0) ^ ((t & 7) << 2)];
        o4.y = yf[(t*128 + g*32 + 4*j + 1) ^ ((t & 7) << 2)];
        o4.z = yf[(t*128 + g*32 + 4*j + 2) ^ ((t & 7) << 2)];
        o4.w = yf[(t*128 + g*32 + 4*j + 3) ^ ((t & 7) << 2)];
        *(float4*)(dst + 4*j) = o4;
      }
    }
    __syncthreads();
  }
}

// ---------------------------------------------------------------------------
extern "C" void kernel_launch(void* const* d_in, const int* in_sizes, int n_in,
                              void* d_out, int out_size, void* d_ws, size_t ws_size,
                              hipStream_t stream)
{
  const float* x      = (const float*)d_in[0];
  const float* qkv_w  = (const float*)d_in[1];
  const float* qkv_b  = (const float*)d_in[2];
  const float* proj_w = (const float*)d_in[3];
  const float* proj_b = (const float*)d_in[4];
  const float* rpb    = (const float*)d_in[5];
  const float* ln1w   = (const float*)d_in[6];
  const float* ln1b   = (const float*)d_in[7];
  const float* ln2w   = (const float*)d_in[8];
  const float* ln2b   = (const float*)d_in[9];
  const float* w1     = (const float*)d_in[10];
  const float* b1     = (const float*)d_in[11];
  const float* w2     = (const float*)d_in[12];
  const float* b2     = (const float*)d_in[13];

  char* ws = (char*)d_ws;
  u16*   qkvwT  = (u16*)(ws + 0);        // 384*128*2  = 98304
  u16*   projwT = (u16*)(ws + 98304);    // 128*128*2  = 32768   -> 131072
  u16*   w1T    = (u16*)(ws + 131072);   // 512*128*2  = 131072  -> 262144
  u16*   w2T    = (u16*)(ws + 262144);   // 128*512*2  = 131072  -> 393216
  float* biasT  = (float*)(ws + 393216); // 8*49*49*4  = 307328  -> 700544
  float* y = (float*)d_out;

  prep_kernel<<<512, 256, 0, stream>>>(qkv_w, proj_w, w1, w2, rpb,
                                       qkvwT, projwT, w1T, w2T, biasT);
  attn_kernel<<<8192, 256, 0, stream>>>(x, ln1w, ln1b, qkv_b, proj_b,
                                        qkvwT, projwT, biasT, y);
  mlp_kernel<<<1568, 256, 0, stream>>>(ln2w, ln2b, b1, b2, w1T, w2T, y);
}

// Round 8
// 2014.197 us; speedup vs baseline: 1.0856x; 1.0856x over previous
//
#include <hip/hip_runtime.h>
#include <hip/hip_bf16.h>

#define DI __device__ __forceinline__

typedef unsigned short u16;
typedef unsigned int   u32;
typedef float  f32x4  __attribute__((ext_vector_type(4)));
typedef __bf16 bf16x8 __attribute__((ext_vector_type(8)));
typedef u16    us8    __attribute__((ext_vector_type(8)));

DI u16 f2bf(float f){
  u32 u = __builtin_bit_cast(u32, f);
  u = (u + 0x7fffu + ((u >> 16) & 1u)) >> 16;
  return (u16)u;
}

DI f32x4 mfma16(bf16x8 a, bf16x8 b, f32x4 c){
  return __builtin_amdgcn_mfma_f32_16x16x32_bf16(a, b, c, 0, 0, 0);
}
DI bf16x8 bzero(){
  us8 z = {0,0,0,0,0,0,0,0};
  return __builtin_bit_cast(bf16x8, z);
}
DI bf16x8 ld8s(const u16* p){ return *(const bf16x8*)p; }

DI f32x4 ldnt4(const float* p){ return __builtin_nontemporal_load((const f32x4*)p); }
DI void stnt4(float* p, f32x4 v){ __builtin_nontemporal_store(v, (f32x4*)p); }

// ---------------------------------------------------------------------------
// Kernel 0: weight prep — bf16 transposed copies + rel-pos bias table
//           TRANSPOSED: biasT[h][key][query]
// ---------------------------------------------------------------------------
__global__ void prep_kernel(const float* __restrict__ qkv_w, const float* __restrict__ proj_w,
                            const float* __restrict__ w1,    const float* __restrict__ w2,
                            const float* __restrict__ rpb,
                            u16* __restrict__ qkvwT, u16* __restrict__ projwT,
                            u16* __restrict__ w1T,   u16* __restrict__ w2T,
                            float* __restrict__ biasT)
{
  const int idx = blockIdx.x * blockDim.x + threadIdx.x;
  const int stride = gridDim.x * blockDim.x;
  for (int i = idx; i < 384*128; i += stride){ int o = i >> 7, k = i & 127; qkvwT[i] = f2bf(qkv_w[k*384 + o]); }
  for (int i = idx; i < 128*128; i += stride){ int o = i >> 7, k = i & 127; projwT[i] = f2bf(proj_w[k*128 + o]); }
  for (int i = idx; i < 512*128; i += stride){ int o = i >> 7, k = i & 127; w1T[i] = f2bf(w1[k*512 + o]); }
  for (int i = idx; i < 128*512; i += stride){ int o = i >> 9, k = i & 511; w2T[i] = f2bf(w2[k*128 + o]); }
  // biasT[h*2401 + key*49 + query] = rpb[REL_IDX[query][key]*8 + h]
  for (int i = idx; i < 8*49*49; i += stride){
    int h = i / 2401, rem = i % 2401, a = rem / 49, b = rem % 49; // a=key, b=query
    int rel = (b/7 - a/7 + 6) * 13 + (b%7 - a%7 + 6);
    biasT[i] = rpb[rel*8 + h];
  }
}

// ---------------------------------------------------------------------------
// Kernel 1: one block = one 7x7 window. LN1 + shift-gather + QKV(MFMA) +
//           MFMA attention (S^T trick, P in registers, 4-head batches) +
//           proj + residual. ao reuses kB's consumed head columns; xn/vT
//           share one pool. LDS 54KB -> 3 blocks/CU.
// ---------------------------------------------------------------------------
__global__ __launch_bounds__(256, 3) void attn_kernel(
    const float* __restrict__ x,
    const float* __restrict__ ln1w, const float* __restrict__ ln1b,
    const float* __restrict__ qkv_b, const float* __restrict__ proj_b,
    const u16* __restrict__ qkvwT, const u16* __restrict__ projwT,
    const float* __restrict__ biasT,
    float* __restrict__ y)
{
  __shared__ u16 qB[64*136];     // q*scale bf16 [tok][ch], padded stride 136
  __shared__ u16 kB[64*136];     // k bf16 [tok][ch] (phase B: ao in consumed cols)
  __shared__ u16 pool[128*72];   // phase A: xn bf16 [64][128] swizzled; phase B: vT [ch][tok] stride 72
  __shared__ float mu_s[64], rs_s[64];
  __shared__ int lab_s[64];

  u16* xw = pool;

  const int tid = threadIdx.x;
  const int lane = tid & 63;
  const int wv = tid >> 6;       // wave 0..3
  const int l15 = lane & 15;
  const int lq  = lane >> 4;     // 0..3
  const int blk = blockIdx.x;
  const int b  = blk >> 8;
  const int wi = blk & 255;
  const int wh = wi >> 4, ww = wi & 15;

  // ---- Stage 1: gather (roll -3,-3) + LN1 -> xw (bf16, swizzled), stats ----
  {
    const int t = tid >> 2;     // token 0..63
    const int g = tid & 3;      // channel quarter
    float vals[32];
    float sum = 0.f, sq = 0.f;
    if (t < 49){
      const int r = t / 7, c = t % 7;
      const int hs   = (wh*7 + r + 3) % 112;
      const int wsrc = (ww*7 + c + 3) % 112;
      const float* src = x + ((size_t)((b*112 + hs)*112 + wsrc))*128 + g*32;
      #pragma unroll
      for (int j = 0; j < 8; j++){
        f32x4 v4 = *(const f32x4*)(src + 4*j);
        vals[4*j+0]=v4[0]; vals[4*j+1]=v4[1]; vals[4*j+2]=v4[2]; vals[4*j+3]=v4[3];
        sum += v4[0] + v4[1] + v4[2] + v4[3];
        sq  += v4[0]*v4[0] + v4[1]*v4[1] + v4[2]*v4[2] + v4[3]*v4[3];
      }
    }
    sum += __shfl_xor(sum, 1); sum += __shfl_xor(sum, 2);
    sq  += __shfl_xor(sq, 1);  sq  += __shfl_xor(sq, 2);
    const float mu = sum * (1.f/128.f);
    const float var = sq * (1.f/128.f) - mu*mu;
    const float rs = rsqrtf(var + 1e-5f);
    if (g == 0){
      mu_s[t] = mu; rs_s[t] = rs;
      const int r = t / 7, c = t % 7;
      const int rh = (wh == 15) ? ((r < 4) ? 1 : 2) : 0;
      const int rw = (ww == 15) ? ((c < 4) ? 1 : 2) : 0;
      lab_s[t] = rh*3 + rw;
    }
    #pragma unroll
    for (int j = 0; j < 32; j++){
      const int ch = g*32 + j;
      float xn = 0.f;
      if (t < 49) xn = (vals[j] - mu) * rs * ln1w[ch] + ln1b[ch];
      xw[(t*128 + ch) ^ ((t & 7) << 3)] = f2bf(xn);
    }
  }
  __syncthreads();

  // ---- Stage 2: QKV GEMM [64x128]@[128x384] -> qB/kB/pool-vT ----
  {
    const f32x4 fz = {0.f,0.f,0.f,0.f};
    f32x4 acc[4][6];
    #pragma unroll
    for (int mt = 0; mt < 4; mt++)
      #pragma unroll
      for (int nt = 0; nt < 6; nt++) acc[mt][nt] = fz;

    const int col0 = wv * 96;
    #pragma unroll
    for (int kk = 0; kk < 4; kk++){
      const int k0 = kk*32 + (lq << 3);
      bf16x8 a[4];
      #pragma unroll
      for (int mt = 0; mt < 4; mt++){
        const int row = mt*16 + l15;
        a[mt] = ld8s(&xw[(row*128 + k0) ^ ((row & 7) << 3)]);
      }
      #pragma unroll
      for (int nt = 0; nt < 6; nt++){
        const int o = col0 + nt*16 + l15;
        const bf16x8 bb = *(const bf16x8*)(qkvwT + o*128 + k0);
        #pragma unroll
        for (int mt = 0; mt < 4; mt++)
          acc[mt][nt] = mfma16(a[mt], bb, acc[mt][nt]);
      }
    }
    __syncthreads();   // all xw reads done before vT overwrites pool
    #pragma unroll
    for (int nt = 0; nt < 6; nt++){
      const int o = col0 + nt*16 + l15;
      const int which = o >> 7;          // 0:q 1:k 2:v
      const int ch = o & 127;
      const float bias = qkv_b[o];
      #pragma unroll
      for (int mt = 0; mt < 4; mt++){
        #pragma unroll
        for (int r = 0; r < 4; r++){
          const int tok = mt*16 + (lq << 2) + r;
          const float v = acc[mt][nt][r] + bias;
          if (which == 0)      qB[tok*136 + ch] = f2bf(v * 0.25f);
          else if (which == 1) kB[tok*136 + ch] = f2bf(v);
          else                 pool[ch*72 + tok] = f2bf(v);
        }
      }
    }
  }
  __syncthreads();

  // ---- Stage 3: MFMA attention, 4-head batches. S^T = mfma(K,Q); softmax
  //      across lq lanes; P repacked via shfl; PV; ao -> kB consumed cols. ----
  {
    const f32x4 fz = {0.f,0.f,0.f,0.f};
    const int iq = wv*16 + l15;            // this lane's query token
    const int labq = lab_s[iq];
    float mterm[4][4];
    #pragma unroll
    for (int nt = 0; nt < 4; nt++)
      #pragma unroll
      for (int r = 0; r < 4; r++){
        const int jk = nt*16 + (lq << 2) + r;   // key token
        float mv = 0.f;
        if (jk >= 49) mv = -1e30f;
        else if (iq < 49 && labq != lab_s[jk]) mv = -100.f;
        mterm[nt][r] = mv;
      }
    #pragma unroll 1
    for (int hb = 0; hb < 2; hb++){
      // --- S for 4 heads (reads kB cols of this batch only) ---
      float p[4][4][4];
      #pragma unroll
      for (int hh = 0; hh < 4; hh++){
        const int h = hb*4 + hh;
        const bf16x8 bq = (lq < 2) ? ld8s(&qB[iq*136 + h*16 + (lq << 3)]) : bzero();
        #pragma unroll
        for (int nt = 0; nt < 4; nt++){
          const bf16x8 ak = (lq < 2) ? ld8s(&kB[(nt*16 + l15)*136 + h*16 + (lq << 3)]) : bzero();
          const f32x4 s4 = mfma16(ak, bq, fz);   // D[key][query]
          #pragma unroll
          for (int r = 0; r < 4; r++){
            const int jk = nt*16 + (lq << 2) + r;
            float s = s4[r] + mterm[nt][r];
            if (jk < 49 && iq < 49) s += biasT[h*2401 + jk*49 + iq];
            p[hh][nt][r] = s;
          }
        }
      }
      // --- softmax, 4 independent chains ---
      #pragma unroll
      for (int hh = 0; hh < 4; hh++){
        float m = -3e38f;
        #pragma unroll
        for (int nt = 0; nt < 4; nt++)
          #pragma unroll
          for (int r = 0; r < 4; r++) m = fmaxf(m, p[hh][nt][r]);
        m = fmaxf(m, __shfl_xor(m, 16));
        m = fmaxf(m, __shfl_xor(m, 32));
        float sum = 0.f;
        #pragma unroll
        for (int nt = 0; nt < 4; nt++)
          #pragma unroll
          for (int r = 0; r < 4; r++){
            const float e = __expf(p[hh][nt][r] - m);
            p[hh][nt][r] = e;
            sum += e;
          }
        sum += __shfl_xor(sum, 16);
        sum += __shfl_xor(sum, 32);
        const float inv = 1.f / sum;
        #pragma unroll
        for (int nt = 0; nt < 4; nt++)
          #pragma unroll
          for (int r = 0; r < 4; r++) p[hh][nt][r] *= inv;
      }
      // --- repack + PV per head -> oaccb (registers) ---
      f32x4 oaccb[4];
      #pragma unroll
      for (int hh = 0; hh < 4; hh++){
        const int h = hb*4 + hh;
        bf16x8 pa[2];
        #pragma unroll
        for (int kk = 0; kk < 2; kk++){
          us8 tmp;
          #pragma unroll
          for (int j = 0; j < 8; j++){
            const int srcLane = ((((lq << 1) + (j >> 2)) & 3) << 4) + l15;
            const float va = __shfl(p[hh][2*kk    ][j & 3], srcLane);
            const float vb = __shfl(p[hh][2*kk + 1][j & 3], srcLane);
            tmp[j] = f2bf((lq & 2) ? vb : va);
          }
          pa[kk] = __builtin_bit_cast(bf16x8, tmp);
        }
        f32x4 oacc = fz;
        #pragma unroll
        for (int kk = 0; kk < 2; kk++){
          const bf16x8 bv = ld8s(&pool[(h*16 + l15)*72 + kk*32 + (lq << 3)]);
          oacc = mfma16(pa[kk], bv, oacc);
        }
        oaccb[hh] = oacc;
      }
      // --- all waves done reading this batch's kB cols -> overwrite with ao ---
      __syncthreads();
      #pragma unroll
      for (int hh = 0; hh < 4; hh++){
        const int h = hb*4 + hh;
        #pragma unroll
        for (int r = 0; r < 4; r++){
          const int tok = wv*16 + (lq << 2) + r;
          kB[tok*136 + h*16 + l15] = f2bf(oaccb[hh][r]);
        }
      }
    }
  }
  __syncthreads();

  // ---- Stage 4: proj [64x128]@[128x128] + residual (ao read from kB) ----
  {
    const f32x4 fz = {0.f,0.f,0.f,0.f};
    f32x4 acc[4][2];
    #pragma unroll
    for (int mt = 0; mt < 4; mt++){ acc[mt][0] = fz; acc[mt][1] = fz; }
    #pragma unroll
    for (int kk = 0; kk < 4; kk++){
      const int k0 = kk*32 + (lq << 3);
      bf16x8 a[4];
      #pragma unroll
      for (int mt = 0; mt < 4; mt++){
        const int row = mt*16 + l15;
        a[mt] = ld8s(&kB[row*136 + k0]);
      }
      #pragma unroll
      for (int nt = 0; nt < 2; nt++){
        const int o = wv*32 + nt*16 + l15;
        const bf16x8 bb = *(const bf16x8*)(projwT + o*128 + k0);
        #pragma unroll
        for (int mt = 0; mt < 4; mt++)
          acc[mt][nt] = mfma16(a[mt], bb, acc[mt][nt]);
      }
    }
    #pragma unroll
    for (int nt = 0; nt < 2; nt++){
      const int ch = wv*32 + nt*16 + l15;
      const float pb = proj_b[ch];
      const float lw = ln1w[ch], lb = ln1b[ch];
      #pragma unroll
      for (int mt = 0; mt < 4; mt++){
        #pragma unroll
        for (int r = 0; r < 4; r++){
          const int tok = mt*16 + (lq << 2) + r;
          if (tok < 49){
            const int rr = tok / 7, cc = tok % 7;
            const int hs   = (wh*7 + rr + 3) % 112;
            const int wsrc = (ww*7 + cc + 3) % 112;
            const size_t gi = ((size_t)((b*112 + hs)*112 + wsrc))*128 + ch;
            const float xn = (x[gi] - mu_s[tok]) * rs_s[tok] * lw + lb;
            y[gi] = xn + acc[mt][nt][r] + pb;
          }
        }
      }
    }
  }
}

// ---------------------------------------------------------------------------
// Kernel 2: MLP over 64-token tiles, in-place on y (= d_out).
// Single bf16 GEMMs; hidden in two 256-col halves; y read ONCE (nontemporal,
// kept in registers); epilogue staged through hid-as-f32 LDS; coalesced
// nontemporal float4 writeback. LDS 48KB -> 3 blocks/CU.
// ---------------------------------------------------------------------------
__global__ __launch_bounds__(256, 3) void mlp_kernel(
    const float* __restrict__ ln2w, const float* __restrict__ ln2b,
    const float* __restrict__ b1, const float* __restrict__ b2,
    const u16* __restrict__ w1T, const u16* __restrict__ w2T,
    float* __restrict__ y)
{
  __shared__ u16 yn[64*128];     // 16KB
  __shared__ u16 hid[64*256];    // 32KB (bf16 hid half; f32 out-stage at end)
  const int tid = threadIdx.x;
  const int lane = tid & 63;
  const int wv = tid >> 6;
  const int l15 = lane & 15;
  const int lq  = lane >> 4;
  const size_t base = (size_t)blockIdx.x * 64;
  const f32x4 fz = {0.f,0.f,0.f,0.f};
  const int t = tid >> 2, g = tid & 3;

  // LN2 -> yn ; y kept in registers (vals)
  float vals[32];
  {
    const float* src = y + (base + t)*128 + g*32;
    float sum = 0.f, sq = 0.f;
    #pragma unroll
    for (int j = 0; j < 8; j++){
      f32x4 v4 = ldnt4(src + 4*j);
      vals[4*j+0]=v4[0]; vals[4*j+1]=v4[1]; vals[4*j+2]=v4[2]; vals[4*j+3]=v4[3];
      sum += v4[0] + v4[1] + v4[2] + v4[3];
      sq  += v4[0]*v4[0] + v4[1]*v4[1] + v4[2]*v4[2] + v4[3]*v4[3];
    }
    sum += __shfl_xor(sum, 1); sum += __shfl_xor(sum, 2);
    sq  += __shfl_xor(sq, 1);  sq  += __shfl_xor(sq, 2);
    const float mu = sum * (1.f/128.f);
    const float rs = rsqrtf(sq * (1.f/128.f) - mu*mu + 1e-5f);
    #pragma unroll
    for (int j = 0; j < 32; j++){
      const int ch = g*32 + j;
      yn[(t*128 + ch) ^ ((t & 7) << 3)] = f2bf((vals[j] - mu) * rs * ln2w[ch] + ln2b[ch]);
    }
  }
  __syncthreads();

  f32x4 acc2[4][2];
  #pragma unroll
  for (int mt = 0; mt < 4; mt++){ acc2[mt][0] = fz; acc2[mt][1] = fz; }

  #pragma unroll 1
  for (int half = 0; half < 2; half++){
    // GEMM1 [64x128]@[128x256] + GELU -> hid
    {
      f32x4 acc[4][4];
      #pragma unroll
      for (int mt = 0; mt < 4; mt++)
        #pragma unroll
        for (int nt = 0; nt < 4; nt++) acc[mt][nt] = fz;
      #pragma unroll
      for (int kk = 0; kk < 4; kk++){
        const int k0 = kk*32 + (lq << 3);
        bf16x8 a[4];
        #pragma unroll
        for (int mt = 0; mt < 4; mt++){
          const int row = mt*16 + l15;
          a[mt] = ld8s(&yn[(row*128 + k0) ^ ((row & 7) << 3)]);
        }
        #pragma unroll
        for (int nt = 0; nt < 4; nt++){
          const int o = half*256 + wv*64 + nt*16 + l15;
          const bf16x8 bb = *(const bf16x8*)(w1T + o*128 + k0);
          #pragma unroll
          for (int mt = 0; mt < 4; mt++)
            acc[mt][nt] = mfma16(a[mt], bb, acc[mt][nt]);
        }
      }
      if (half == 1) __syncthreads();   // half0's GEMM2 reads done before overwrite
      #pragma unroll
      for (int nt = 0; nt < 4; nt++){
        const int o = half*256 + wv*64 + nt*16 + l15;
        const int cl = o - half*256;           // local col 0..255
        const float bb1 = b1[o];
        #pragma unroll
        for (int mt = 0; mt < 4; mt++){
          #pragma unroll
          for (int r = 0; r < 4; r++){
            const int tok = mt*16 + (lq << 2) + r;
            const float v = acc[mt][nt][r] + bb1;
            const float u = 0.7978845608028654f * (v + 0.044715f * v*v*v);
            const float th = 1.f - 2.f / (__expf(2.f*u) + 1.f);
            const float gel = 0.5f * v * (1.f + th);
            hid[(tok*256 + cl) ^ ((tok & 7) << 3)] = f2bf(gel);
          }
        }
      }
    }
    __syncthreads();

    // GEMM2 partial: [64x256]@[256x128], accumulate acc2
    {
      #pragma unroll
      for (int kk = 0; kk < 8; kk++){
        const int k0 = kk*32 + (lq << 3);      // local k in half: 0..255
        bf16x8 a[4];
        #pragma unroll
        for (int mt = 0; mt < 4; mt++){
          const int row = mt*16 + l15;
          a[mt] = ld8s(&hid[(row*256 + k0) ^ ((row & 7) << 3)]);
        }
        #pragma unroll
        for (int nt = 0; nt < 2; nt++){
          const int o = wv*32 + nt*16 + l15;
          const int kg = half*256 + k0;
          const bf16x8 bb = *(const bf16x8*)(w2T + o*512 + kg);
          #pragma unroll
          for (int mt = 0; mt < 4; mt++)
            acc2[mt][nt] = mfma16(a[mt], bb, acc2[mt][nt]);
        }
      }
    }
  }
  __syncthreads();   // last GEMM2 hid reads done

  // epilogue: stage acc2(+b2) into hid reinterpreted as f32 [64][128]
  {
    float* hidf = (float*)hid;
    #pragma unroll
    for (int nt = 0; nt < 2; nt++){
      const int ch = wv*32 + nt*16 + l15;
      const float bb2 = b2[ch];
      #pragma unroll
      for (int mt = 0; mt < 4; mt++){
        #pragma unroll
        for (int r = 0; r < 4; r++){
          const int tok = mt*16 + (lq << 2) + r;
          hidf[(tok*128 + ch) ^ ((tok & 7) << 2)] = acc2[mt][nt][r] + bb2;
        }
      }
    }
  }
  __syncthreads();

  // coalesced nontemporal float4 writeback: out = y(regs) + hid
  {
    const float* hidf = (const float*)hid;
    float* dst = y + (base + t)*128 + g*32;
    #pragma unroll
    for (int j = 0; j < 8; j++){
      const int idx = ((t*128 + g*32 + 4*j) ^ ((t & 7) << 2));
      f32x4 h4 = *(const f32x4*)(hidf + idx);
      f32x4 o4;
      o4[0] = vals[4*j+0] + h4[0];
      o4[1] = vals[4*j+1] + h4[1];
      o4[2] = vals[4*j+2] + h4[2];
      o4[3] = vals[4*j+3] + h4[3];
      stnt4(dst + 4*j, o4);
    }
  }
}

// ---------------------------------------------------------------------------
extern "C" void kernel_launch(void* const* d_in, const int* in_sizes, int n_in,
                              void* d_out, int out_size, void* d_ws, size_t ws_size,
                              hipStream_t stream)
{
  const float* x      = (const float*)d_in[0];
  const float* qkv_w  = (const float*)d_in[1];
  const float* qkv_b  = (const float*)d_in[2];
  const float* proj_w = (const float*)d_in[3];
  const float* proj_b = (const float*)d_in[4];
  const float* rpb    = (const float*)d_in[5];
  const float* ln1w   = (const float*)d_in[6];
  const float* ln1b   = (const float*)d_in[7];
  const float* ln2w   = (const float*)d_in[8];
  const float* ln2b   = (const float*)d_in[9];
  const float* w1     = (const float*)d_in[10];
  const float* b1     = (const float*)d_in[11];
  const float* w2     = (const float*)d_in[12];
  const float* b2     = (const float*)d_in[13];

  char* ws = (char*)d_ws;
  u16*   qkvwT  = (u16*)(ws + 0);        // 384*128*2  = 98304
  u16*   projwT = (u16*)(ws + 98304);    // 128*128*2  = 32768   -> 131072
  u16*   w1T    = (u16*)(ws + 131072);   // 512*128*2  = 131072  -> 262144
  u16*   w2T    = (u16*)(ws + 262144);   // 128*512*2  = 131072  -> 393216
  float* biasT  = (float*)(ws + 393216); // 8*49*49*4  = 307328  -> 700544
  float* y = (float*)d_out;

  prep_kernel<<<512, 256, 0, stream>>>(qkv_w, proj_w, w1, w2, rpb,
                                       qkvwT, projwT, w1T, w2T, biasT);
  attn_kernel<<<8192, 256, 0, stream>>>(x, ln1w, ln1b, qkv_b, proj_b,
                                        qkvwT, projwT, biasT, y);
  mlp_kernel<<<6272, 256, 0, stream>>>(ln2w, ln2b, b1, b2, w1T, w2T, y);
}

// Round 9
// 1805.332 us; speedup vs baseline: 1.2112x; 1.1157x over previous
//
#include <hip/hip_runtime.h>
#include <hip/hip_bf16.h>

#define DI __device__ __forceinline__

typedef unsigned short u16;
typedef unsigned int   u32;
typedef float  f32x4  __attribute__((ext_vector_type(4)));
typedef __bf16 bf16x8 __attribute__((ext_vector_type(8)));
typedef u16    us8    __attribute__((ext_vector_type(8)));

DI u16 f2bf(float f){
  u32 u = __builtin_bit_cast(u32, f);
  u = (u + 0x7fffu + ((u >> 16) & 1u)) >> 16;
  return (u16)u;
}
DI float bf2f(u16 h){
  u32 u = ((u32)h) << 16;
  return __builtin_bit_cast(float, u);
}

DI f32x4 mfma16(bf16x8 a, bf16x8 b, f32x4 c){
  return __builtin_amdgcn_mfma_f32_16x16x32_bf16(a, b, c, 0, 0, 0);
}
DI bf16x8 bzero(){
  us8 z = {0,0,0,0,0,0,0,0};
  return __builtin_bit_cast(bf16x8, z);
}
DI bf16x8 ld8s(const u16* p){ return *(const bf16x8*)p; }

// ---------------------------------------------------------------------------
// Kernel 0: weight prep — bf16 transposed copies + rel-pos bias table
//           TRANSPOSED: biasT[h][key][query]
// ---------------------------------------------------------------------------
__global__ void prep_kernel(const float* __restrict__ qkv_w, const float* __restrict__ proj_w,
                            const float* __restrict__ w1,    const float* __restrict__ w2,
                            const float* __restrict__ rpb,
                            u16* __restrict__ qkvwT, u16* __restrict__ projwT,
                            u16* __restrict__ w1T,   u16* __restrict__ w2T,
                            float* __restrict__ biasT)
{
  const int idx = blockIdx.x * blockDim.x + threadIdx.x;
  const int stride = gridDim.x * blockDim.x;
  for (int i = idx; i < 384*128; i += stride){ int o = i >> 7, k = i & 127; qkvwT[i] = f2bf(qkv_w[k*384 + o]); }
  for (int i = idx; i < 128*128; i += stride){ int o = i >> 7, k = i & 127; projwT[i] = f2bf(proj_w[k*128 + o]); }
  for (int i = idx; i < 512*128; i += stride){ int o = i >> 7, k = i & 127; w1T[i] = f2bf(w1[k*512 + o]); }
  for (int i = idx; i < 128*512; i += stride){ int o = i >> 9, k = i & 511; w2T[i] = f2bf(w2[k*128 + o]); }
  // biasT[h*2401 + key*49 + query] = rpb[REL_IDX[query][key]*8 + h]
  for (int i = idx; i < 8*49*49; i += stride){
    int h = i / 2401, rem = i % 2401, a = rem / 49, b = rem % 49; // a=key, b=query
    int rel = (b/7 - a/7 + 6) * 13 + (b%7 - a%7 + 6);
    biasT[i] = rpb[rel*8 + h];
  }
}

// ---------------------------------------------------------------------------
// Kernel 1: one block = one 7x7 window. LN1 + shift-gather + QKV(MFMA) +
//           MFMA attention (S^T trick, P in registers, 4-head batches) +
//           proj + residual. ao reuses kB's consumed head columns; xn kept
//           packed-bf16 in regs; final y write coalesced via f32 LDS stage.
// ---------------------------------------------------------------------------
__global__ __launch_bounds__(256, 3) void attn_kernel(
    const float* __restrict__ x,
    const float* __restrict__ ln1w, const float* __restrict__ ln1b,
    const float* __restrict__ qkv_b, const float* __restrict__ proj_b,
    const u16* __restrict__ qkvwT, const u16* __restrict__ projwT,
    const float* __restrict__ biasT,
    float* __restrict__ y)
{
  __shared__ u16 qkPool[2*64*136]; // qB | kB ; stage-4 overlay: aoS f32[64*128]
  __shared__ u16 pool[128*72];     // phase A: xn bf16 [64][128] swz; phase B: vT stride 72
  __shared__ int lab_s[64];

  u16* qB = qkPool;
  u16* kB = qkPool + 64*136;
  u16* xw = pool;
  float* aoS = (float*)qkPool;

  const int tid = threadIdx.x;
  const int lane = tid & 63;
  const int wv = tid >> 6;       // wave 0..3
  const int l15 = lane & 15;
  const int lq  = lane >> 4;     // 0..3
  const int blk = blockIdx.x;
  const int b  = blk >> 8;
  const int wi = blk & 255;
  const int wh = wi >> 4, ww = wi & 15;
  const int t = tid >> 2, g = tid & 3;   // token / channel-quarter roles

  u32 xnp[16];                   // xn (bf16 pairs) for (t, g*32..g*32+31)

  // ---- Stage 1: gather (roll -3,-3) + LN1 -> xw (bf16, swizzled) + xnp ----
  {
    float vals[32];
    float sum = 0.f, sq = 0.f;
    if (t < 49){
      const int r = t / 7, c = t % 7;
      const int hs   = (wh*7 + r + 3) % 112;
      const int wsrc = (ww*7 + c + 3) % 112;
      const float* src = x + ((size_t)((b*112 + hs)*112 + wsrc))*128 + g*32;
      #pragma unroll
      for (int j = 0; j < 8; j++){
        f32x4 v4 = *(const f32x4*)(src + 4*j);
        vals[4*j+0]=v4[0]; vals[4*j+1]=v4[1]; vals[4*j+2]=v4[2]; vals[4*j+3]=v4[3];
        sum += v4[0] + v4[1] + v4[2] + v4[3];
        sq  += v4[0]*v4[0] + v4[1]*v4[1] + v4[2]*v4[2] + v4[3]*v4[3];
      }
    } else {
      #pragma unroll
      for (int j = 0; j < 32; j++) vals[j] = 0.f;
    }
    sum += __shfl_xor(sum, 1); sum += __shfl_xor(sum, 2);
    sq  += __shfl_xor(sq, 1);  sq  += __shfl_xor(sq, 2);
    const float mu = sum * (1.f/128.f);
    const float var = sq * (1.f/128.f) - mu*mu;
    const float rs = rsqrtf(var + 1e-5f);
    if (g == 0){
      const int r = t / 7, c = t % 7;
      const int rh = (wh == 15) ? ((r < 4) ? 1 : 2) : 0;
      const int rw = (ww == 15) ? ((c < 4) ? 1 : 2) : 0;
      lab_s[t] = rh*3 + rw;
    }
    #pragma unroll
    for (int j = 0; j < 32; j++){
      const int ch = g*32 + j;
      float xn = 0.f;
      if (t < 49) xn = (vals[j] - mu) * rs * ln1w[ch] + ln1b[ch];
      const u16 h = f2bf(xn);
      xw[(t*128 + ch) ^ ((t & 7) << 3)] = h;
      if (j & 1) xnp[j >> 1] |= ((u32)h << 16);
      else       xnp[j >> 1]  = (u32)h;
    }
  }
  __syncthreads();

  // ---- Stage 2: QKV GEMM [64x128]@[128x384] -> qB/kB/pool-vT ----
  {
    const f32x4 fz = {0.f,0.f,0.f,0.f};
    f32x4 acc[4][6];
    #pragma unroll
    for (int mt = 0; mt < 4; mt++)
      #pragma unroll
      for (int nt = 0; nt < 6; nt++) acc[mt][nt] = fz;

    const int col0 = wv * 96;
    #pragma unroll
    for (int kk = 0; kk < 4; kk++){
      const int k0 = kk*32 + (lq << 3);
      bf16x8 a[4];
      #pragma unroll
      for (int mt = 0; mt < 4; mt++){
        const int row = mt*16 + l15;
        a[mt] = ld8s(&xw[(row*128 + k0) ^ ((row & 7) << 3)]);
      }
      #pragma unroll
      for (int nt = 0; nt < 6; nt++){
        const int o = col0 + nt*16 + l15;
        const bf16x8 bb = *(const bf16x8*)(qkvwT + o*128 + k0);
        #pragma unroll
        for (int mt = 0; mt < 4; mt++)
          acc[mt][nt] = mfma16(a[mt], bb, acc[mt][nt]);
      }
    }
    __syncthreads();   // all xw reads done before vT overwrites pool
    #pragma unroll
    for (int nt = 0; nt < 6; nt++){
      const int o = col0 + nt*16 + l15;
      const int which = o >> 7;          // 0:q 1:k 2:v
      const int ch = o & 127;
      const float bias = qkv_b[o];
      #pragma unroll
      for (int mt = 0; mt < 4; mt++){
        #pragma unroll
        for (int r = 0; r < 4; r++){
          const int tok = mt*16 + (lq << 2) + r;
          const float v = acc[mt][nt][r] + bias;
          if (which == 0)      qB[tok*136 + ch] = f2bf(v * 0.25f);
          else if (which == 1) kB[tok*136 + ch] = f2bf(v);
          else                 pool[ch*72 + tok] = f2bf(v);
        }
      }
    }
  }
  __syncthreads();

  // ---- Stage 3: MFMA attention, 4-head batches. S^T = mfma(K,Q); softmax
  //      across lq lanes; P repacked via shfl; PV; ao -> kB consumed cols. ----
  {
    const f32x4 fz = {0.f,0.f,0.f,0.f};
    const int iq = wv*16 + l15;            // this lane's query token
    const int labq = lab_s[iq];
    float mterm[4][4];
    #pragma unroll
    for (int nt = 0; nt < 4; nt++)
      #pragma unroll
      for (int r = 0; r < 4; r++){
        const int jk = nt*16 + (lq << 2) + r;   // key token
        float mv = 0.f;
        if (jk >= 49) mv = -1e30f;
        else if (iq < 49 && labq != lab_s[jk]) mv = -100.f;
        mterm[nt][r] = mv;
      }
    #pragma unroll 1
    for (int hb = 0; hb < 2; hb++){
      // --- S for 4 heads (reads kB cols of this batch only) ---
      float p[4][4][4];
      #pragma unroll
      for (int hh = 0; hh < 4; hh++){
        const int h = hb*4 + hh;
        const bf16x8 bq = (lq < 2) ? ld8s(&qB[iq*136 + h*16 + (lq << 3)]) : bzero();
        #pragma unroll
        for (int nt = 0; nt < 4; nt++){
          const bf16x8 ak = (lq < 2) ? ld8s(&kB[(nt*16 + l15)*136 + h*16 + (lq << 3)]) : bzero();
          const f32x4 s4 = mfma16(ak, bq, fz);   // D[key][query]
          #pragma unroll
          for (int r = 0; r < 4; r++){
            const int jk = nt*16 + (lq << 2) + r;
            float s = s4[r] + mterm[nt][r];
            if (jk < 49 && iq < 49) s += biasT[h*2401 + jk*49 + iq];
            p[hh][nt][r] = s;
          }
        }
      }
      // --- softmax, 4 independent chains ---
      #pragma unroll
      for (int hh = 0; hh < 4; hh++){
        float m = -3e38f;
        #pragma unroll
        for (int nt = 0; nt < 4; nt++)
          #pragma unroll
          for (int r = 0; r < 4; r++) m = fmaxf(m, p[hh][nt][r]);
        m = fmaxf(m, __shfl_xor(m, 16));
        m = fmaxf(m, __shfl_xor(m, 32));
        float sum = 0.f;
        #pragma unroll
        for (int nt = 0; nt < 4; nt++)
          #pragma unroll
          for (int r = 0; r < 4; r++){
            const float e = __expf(p[hh][nt][r] - m);
            p[hh][nt][r] = e;
            sum += e;
          }
        sum += __shfl_xor(sum, 16);
        sum += __shfl_xor(sum, 32);
        const float inv = 1.f / sum;
        #pragma unroll
        for (int nt = 0; nt < 4; nt++)
          #pragma unroll
          for (int r = 0; r < 4; r++) p[hh][nt][r] *= inv;
      }
      // --- repack + PV per head -> oaccb (registers) ---
      f32x4 oaccb[4];
      #pragma unroll
      for (int hh = 0; hh < 4; hh++){
        const int h = hb*4 + hh;
        bf16x8 pa[2];
        #pragma unroll
        for (int kk = 0; kk < 2; kk++){
          us8 tmp;
          #pragma unroll
          for (int j = 0; j < 8; j++){
            const int srcLane = ((((lq << 1) + (j >> 2)) & 3) << 4) + l15;
            const float va = __shfl(p[hh][2*kk    ][j & 3], srcLane);
            const float vb = __shfl(p[hh][2*kk + 1][j & 3], srcLane);
            tmp[j] = f2bf((lq & 2) ? vb : va);
          }
          pa[kk] = __builtin_bit_cast(bf16x8, tmp);
        }
        f32x4 oacc = fz;
        #pragma unroll
        for (int kk = 0; kk < 2; kk++){
          const bf16x8 bv = ld8s(&pool[(h*16 + l15)*72 + kk*32 + (lq << 3)]);
          oacc = mfma16(pa[kk], bv, oacc);
        }
        oaccb[hh] = oacc;
      }
      // --- all waves done reading this batch's kB cols -> overwrite with ao ---
      __syncthreads();
      #pragma unroll
      for (int hh = 0; hh < 4; hh++){
        const int h = hb*4 + hh;
        #pragma unroll
        for (int r = 0; r < 4; r++){
          const int tok = wv*16 + (lq << 2) + r;
          kB[tok*136 + h*16 + l15] = f2bf(oaccb[hh][r]);
        }
      }
    }
  }
  __syncthreads();

  // ---- Stage 4: proj [64x128]@[128x128]; stage result in aoS; coalesced
  //      residual write from (t,g) threads using packed xn. ----
  {
    const f32x4 fz = {0.f,0.f,0.f,0.f};
    f32x4 acc[4][2];
    #pragma unroll
    for (int mt = 0; mt < 4; mt++){ acc[mt][0] = fz; acc[mt][1] = fz; }
    #pragma unroll
    for (int kk = 0; kk < 4; kk++){
      const int k0 = kk*32 + (lq << 3);
      bf16x8 a[4];
      #pragma unroll
      for (int mt = 0; mt < 4; mt++){
        const int row = mt*16 + l15;
        a[mt] = ld8s(&kB[row*136 + k0]);
      }
      #pragma unroll
      for (int nt = 0; nt < 2; nt++){
        const int o = wv*32 + nt*16 + l15;
        const bf16x8 bb = *(const bf16x8*)(projwT + o*128 + k0);
        #pragma unroll
        for (int mt = 0; mt < 4; mt++)
          acc[mt][nt] = mfma16(a[mt], bb, acc[mt][nt]);
      }
    }
    __syncthreads();   // all kB reads done before aoS overlay write
    #pragma unroll
    for (int nt = 0; nt < 2; nt++){
      const int ch = wv*32 + nt*16 + l15;
      const float pb = proj_b[ch];
      #pragma unroll
      for (int mt = 0; mt < 4; mt++){
        #pragma unroll
        for (int r = 0; r < 4; r++){
          const int tok = mt*16 + (lq << 2) + r;
          aoS[(tok*128 + ch) ^ ((tok & 7) << 2)] = acc[mt][nt][r] + pb;
        }
      }
    }
  }
  __syncthreads();

  // ---- Final: y = xn(packed regs) + aoS, coalesced full-row writes ----
  if (t < 49){
    const int rr = t / 7, cc = t % 7;
    const int hs   = (wh*7 + rr + 3) % 112;
    const int wsrc = (ww*7 + cc + 3) % 112;
    float* dst = y + ((size_t)((b*112 + hs)*112 + wsrc))*128 + g*32;
    #pragma unroll
    for (int j = 0; j < 8; j++){
      const int idx = (t*128 + g*32 + 4*j) ^ ((t & 7) << 2);
      const f32x4 a4 = *(const f32x4*)(aoS + idx);
      f32x4 o4;
      #pragma unroll
      for (int e = 0; e < 4; e++){
        const int c = 4*j + e;
        const u16 h = (u16)(xnp[c >> 1] >> ((c & 1) * 16));
        o4[e] = bf2f(h) + a4[e];
      }
      *(f32x4*)(dst + 4*j) = o4;
    }
  }
}

// ---------------------------------------------------------------------------
// Kernel 2: MLP over 64-token tiles, in-place on y (= d_out).
// Single bf16 GEMMs; hidden in two 256-col halves; y read once (regs);
// residual added in LDS; flat fully-contiguous writeback. 48KB -> 3 blk/CU.
// ---------------------------------------------------------------------------
__global__ __launch_bounds__(256, 3) void mlp_kernel(
    const float* __restrict__ ln2w, const float* __restrict__ ln2b,
    const float* __restrict__ b1, const float* __restrict__ b2,
    const u16* __restrict__ w1T, const u16* __restrict__ w2T,
    float* __restrict__ y)
{
  __shared__ u16 yn[64*128];     // 16KB
  __shared__ u16 hid[64*256];    // 32KB (bf16 hid half; f32 out-stage at end)
  const int tid = threadIdx.x;
  const int lane = tid & 63;
  const int wv = tid >> 6;
  const int l15 = lane & 15;
  const int lq  = lane >> 4;
  const size_t base = (size_t)blockIdx.x * 64;
  const f32x4 fz = {0.f,0.f,0.f,0.f};
  const int t = tid >> 2, g = tid & 3;

  // LN2 -> yn ; y kept in registers (vals)
  float vals[32];
  {
    const float* src = y + (base + t)*128 + g*32;
    float sum = 0.f, sq = 0.f;
    #pragma unroll
    for (int j = 0; j < 8; j++){
      f32x4 v4 = *(const f32x4*)(src + 4*j);
      vals[4*j+0]=v4[0]; vals[4*j+1]=v4[1]; vals[4*j+2]=v4[2]; vals[4*j+3]=v4[3];
      sum += v4[0] + v4[1] + v4[2] + v4[3];
      sq  += v4[0]*v4[0] + v4[1]*v4[1] + v4[2]*v4[2] + v4[3]*v4[3];
    }
    sum += __shfl_xor(sum, 1); sum += __shfl_xor(sum, 2);
    sq  += __shfl_xor(sq, 1);  sq  += __shfl_xor(sq, 2);
    const float mu = sum * (1.f/128.f);
    const float rs = rsqrtf(sq * (1.f/128.f) - mu*mu + 1e-5f);
    #pragma unroll
    for (int j = 0; j < 32; j++){
      const int ch = g*32 + j;
      yn[(t*128 + ch) ^ ((t & 7) << 3)] = f2bf((vals[j] - mu) * rs * ln2w[ch] + ln2b[ch]);
    }
  }
  __syncthreads();

  f32x4 acc2[4][2];
  #pragma unroll
  for (int mt = 0; mt < 4; mt++){ acc2[mt][0] = fz; acc2[mt][1] = fz; }

  #pragma unroll 1
  for (int half = 0; half < 2; half++){
    // GEMM1 [64x128]@[128x256] + GELU -> hid
    {
      f32x4 acc[4][4];
      #pragma unroll
      for (int mt = 0; mt < 4; mt++)
        #pragma unroll
        for (int nt = 0; nt < 4; nt++) acc[mt][nt] = fz;
      #pragma unroll
      for (int kk = 0; kk < 4; kk++){
        const int k0 = kk*32 + (lq << 3);
        bf16x8 a[4];
        #pragma unroll
        for (int mt = 0; mt < 4; mt++){
          const int row = mt*16 + l15;
          a[mt] = ld8s(&yn[(row*128 + k0) ^ ((row & 7) << 3)]);
        }
        #pragma unroll
        for (int nt = 0; nt < 4; nt++){
          const int o = half*256 + wv*64 + nt*16 + l15;
          const bf16x8 bb = *(const bf16x8*)(w1T + o*128 + k0);
          #pragma unroll
          for (int mt = 0; mt < 4; mt++)
            acc[mt][nt] = mfma16(a[mt], bb, acc[mt][nt]);
        }
      }
      if (half == 1) __syncthreads();   // half0's GEMM2 reads done before overwrite
      #pragma unroll
      for (int nt = 0; nt < 4; nt++){
        const int o = half*256 + wv*64 + nt*16 + l15;
        const int cl = o - half*256;           // local col 0..255
        const float bb1 = b1[o];
        #pragma unroll
        for (int mt = 0; mt < 4; mt++){
          #pragma unroll
          for (int r = 0; r < 4; r++){
            const int tok = mt*16 + (lq << 2) + r;
            const float v = acc[mt][nt][r] + bb1;
            const float u = 0.7978845608028654f * (v + 0.044715f * v*v*v);
            const float th = 1.f - 2.f / (__expf(2.f*u) + 1.f);
            const float gel = 0.5f * v * (1.f + th);
            hid[(tok*256 + cl) ^ ((tok & 7) << 3)] = f2bf(gel);
          }
        }
      }
    }
    __syncthreads();

    // GEMM2 partial: [64x256]@[256x128], accumulate acc2
    {
      #pragma unroll
      for (int kk = 0; kk < 8; kk++){
        const int k0 = kk*32 + (lq << 3);      // local k in half: 0..255
        bf16x8 a[4];
        #pragma unroll
        for (int mt = 0; mt < 4; mt++){
          const int row = mt*16 + l15;
          a[mt] = ld8s(&hid[(row*256 + k0) ^ ((row & 7) << 3)]);
        }
        #pragma unroll
        for (int nt = 0; nt < 2; nt++){
          const int o = wv*32 + nt*16 + l15;
          const int kg = half*256 + k0;
          const bf16x8 bb = *(const bf16x8*)(w2T + o*512 + kg);
          #pragma unroll
          for (int mt = 0; mt < 4; mt++)
            acc2[mt][nt] = mfma16(a[mt], bb, acc2[mt][nt]);
        }
      }
    }
  }
  __syncthreads();   // last GEMM2 hid reads done

  // epilogue: stage acc2(+b2) into hid reinterpreted as f32 [64][128]
  float* hidf = (float*)hid;
  {
    #pragma unroll
    for (int nt = 0; nt < 2; nt++){
      const int ch = wv*32 + nt*16 + l15;
      const float bb2 = b2[ch];
      #pragma unroll
      for (int mt = 0; mt < 4; mt++){
        #pragma unroll
        for (int r = 0; r < 4; r++){
          const int tok = mt*16 + (lq << 2) + r;
          hidf[(tok*128 + ch) ^ ((tok & 7) << 2)] = acc2[mt][nt][r] + bb2;
        }
      }
    }
  }
  __syncthreads();

  // residual add in LDS: (t,g) thread owns (t, g*32..+31)
  {
    #pragma unroll
    for (int j = 0; j < 32; j++){
      const int idx = (t*128 + g*32 + j) ^ ((t & 7) << 2);
      hidf[idx] += vals[j];
    }
  }
  __syncthreads();

  // flat fully-contiguous writeback: each wave-instruction stores 1KB
  {
    #pragma unroll
    for (int it = 0; it < 8; it++){
      const int flat = it*1024 + tid*4;
      const int tok = flat >> 7;
      const f32x4 v = *(const f32x4*)(hidf + (flat ^ ((tok & 7) << 2)));
      *(f32x4*)(y + base*128 + flat) = v;
    }
  }
}

// ---------------------------------------------------------------------------
extern "C" void kernel_launch(void* const* d_in, const int* in_sizes, int n_in,
                              void* d_out, int out_size, void* d_ws, size_t ws_size,
                              hipStream_t stream)
{
  const float* x      = (const float*)d_in[0];
  const float* qkv_w  = (const float*)d_in[1];
  const float* qkv_b  = (const float*)d_in[2];
  const float* proj_w = (const float*)d_in[3];
  const float* proj_b = (const float*)d_in[4];
  const float* rpb    = (const float*)d_in[5];
  const float* ln1w   = (const float*)d_in[6];
  const float* ln1b   = (const float*)d_in[7];
  const float* ln2w   = (const float*)d_in[8];
  const float* ln2b   = (const float*)d_in[9];
  const float* w1     = (const float*)d_in[10];
  const float* b1     = (const float*)d_in[11];
  const float* w2     = (const float*)d_in[12];
  const float* b2     = (const float*)d_in[13];

  char* ws = (char*)d_ws;
  u16*   qkvwT  = (u16*)(ws + 0);        // 384*128*2  = 98304
  u16*   projwT = (u16*)(ws + 98304);    // 128*128*2  = 32768   -> 131072
  u16*   w1T    = (u16*)(ws + 131072);   // 512*128*2  = 131072  -> 262144
  u16*   w2T    = (u16*)(ws + 262144);   // 128*512*2  = 131072  -> 393216
  float* biasT  = (float*)(ws + 393216); // 8*49*49*4  = 307328  -> 700544
  float* y = (float*)d_out;

  prep_kernel<<<512, 256, 0, stream>>>(qkv_w, proj_w, w1, w2, rpb,
                                       qkvwT, projwT, w1T, w2T, biasT);
  attn_kernel<<<8192, 256, 0, stream>>>(x, ln1w, ln1b, qkv_b, proj_b,
                                        qkvwT, projwT, biasT, y);
  mlp_kernel<<<6272, 256, 0, stream>>>(ln2w, ln2b, b1, b2, w1T, w2T, y);
}

// Round 10
// 1700.650 us; speedup vs baseline: 1.2857x; 1.0616x over previous
//
#include <hip/hip_runtime.h>
#include <hip/hip_bf16.h>

#define DI __device__ __forceinline__

typedef unsigned short u16;
typedef unsigned int   u32;
typedef float  f32x4  __attribute__((ext_vector_type(4)));
typedef __bf16 bf16x8 __attribute__((ext_vector_type(8)));
typedef u16    us8    __attribute__((ext_vector_type(8)));

DI u16 f2bf(float f){
  u32 u = __builtin_bit_cast(u32, f);
  u = (u + 0x7fffu + ((u >> 16) & 1u)) >> 16;
  return (u16)u;
}
DI float bf2f(u16 h){
  u32 u = ((u32)h) << 16;
  return __builtin_bit_cast(float, u);
}

DI f32x4 mfma16(bf16x8 a, bf16x8 b, f32x4 c){
  return __builtin_amdgcn_mfma_f32_16x16x32_bf16(a, b, c, 0, 0, 0);
}
DI bf16x8 bzero(){
  us8 z = {0,0,0,0,0,0,0,0};
  return __builtin_bit_cast(bf16x8, z);
}
DI bf16x8 ld8s(const u16* p){ return *(const bf16x8*)p; }

// ---------------------------------------------------------------------------
// Kernel 0: weight prep — bf16 transposed copies + 4 class-fused bias+mask
//           tables biasC[cls][h][key64][query64] (f32, padding baked in).
// ---------------------------------------------------------------------------
__global__ void prep_kernel(const float* __restrict__ qkv_w, const float* __restrict__ proj_w,
                            const float* __restrict__ w1,    const float* __restrict__ w2,
                            const float* __restrict__ rpb,
                            u16* __restrict__ qkvwT, u16* __restrict__ projwT,
                            u16* __restrict__ w1T,   u16* __restrict__ w2T,
                            float* __restrict__ biasC)
{
  const int idx = blockIdx.x * blockDim.x + threadIdx.x;
  const int stride = gridDim.x * blockDim.x;
  for (int i = idx; i < 384*128; i += stride){ int o = i >> 7, k = i & 127; qkvwT[i] = f2bf(qkv_w[k*384 + o]); }
  for (int i = idx; i < 128*128; i += stride){ int o = i >> 7, k = i & 127; projwT[i] = f2bf(proj_w[k*128 + o]); }
  for (int i = idx; i < 512*128; i += stride){ int o = i >> 7, k = i & 127; w1T[i] = f2bf(w1[k*512 + o]); }
  for (int i = idx; i < 128*512; i += stride){ int o = i >> 9, k = i & 511; w2T[i] = f2bf(w2[k*128 + o]); }
  // biasC[cls*32768 + h*4096 + key*64 + query]
  for (int i = idx; i < 4*8*64*64; i += stride){
    const int cls = i >> 15;
    const int rem = i & 32767;
    const int h = rem >> 12;
    const int km = rem & 4095;
    const int key = km >> 6, q = km & 63;
    float v;
    if (key >= 49) v = -1e30f;
    else if (q >= 49) v = 0.f;
    else {
      const int rel = (q/7 - key/7 + 6)*13 + (q%7 - key%7 + 6);
      v = rpb[rel*8 + h];
      const int rhF = cls >> 1, rwF = cls & 1;
      const int labq = (rhF ? ((q/7)   < 4 ? 1 : 2) : 0)*3 + (rwF ? ((q%7)   < 4 ? 1 : 2) : 0);
      const int labk = (rhF ? ((key/7) < 4 ? 1 : 2) : 0)*3 + (rwF ? ((key%7) < 4 ? 1 : 2) : 0);
      if (labq != labk) v -= 100.f;
    }
    biasC[i] = v;
  }
}

// ---------------------------------------------------------------------------
// Kernel 1: one block = one 7x7 window. LN1 + shift-gather + QKV(MFMA) +
//           MFMA attention (S^T trick, bias+mask as MFMA C-input, P in regs,
//           4-head batches) + proj + residual (coalesced via LDS stage).
// ---------------------------------------------------------------------------
__global__ __launch_bounds__(256, 3) void attn_kernel(
    const float* __restrict__ x,
    const float* __restrict__ ln1w, const float* __restrict__ ln1b,
    const float* __restrict__ qkv_b, const float* __restrict__ proj_b,
    const u16* __restrict__ qkvwT, const u16* __restrict__ projwT,
    const float* __restrict__ biasC,
    float* __restrict__ y)
{
  __shared__ u16 qkPool[2*64*136]; // qB | kB ; stage-4 overlay: aoS f32[64*128]
  __shared__ u16 pool[128*72];     // phase A: xn bf16 [64][128] swz; phase B: vT stride 72

  u16* qB = qkPool;
  u16* kB = qkPool + 64*136;
  u16* xw = pool;
  float* aoS = (float*)qkPool;

  const int tid = threadIdx.x;
  const int lane = tid & 63;
  const int wv = tid >> 6;       // wave 0..3
  const int l15 = lane & 15;
  const int lq  = lane >> 4;     // 0..3
  const int blk = blockIdx.x;
  const int b  = blk >> 8;
  const int wi = blk & 255;
  const int wh = wi >> 4, ww = wi & 15;
  const int cls = ((wh == 15) ? 2 : 0) + ((ww == 15) ? 1 : 0);
  const int t = tid >> 2, g = tid & 3;   // token / channel-quarter roles

  u32 xnp[16];                   // xn (bf16 pairs) for (t, g*32..g*32+31)

  // ---- Stage 1: gather (roll -3,-3) + LN1 -> xw (bf16, swizzled) + xnp ----
  {
    float vals[32];
    float sum = 0.f, sq = 0.f;
    if (t < 49){
      const int r = t / 7, c = t % 7;
      const int hs   = (wh*7 + r + 3) % 112;
      const int wsrc = (ww*7 + c + 3) % 112;
      const float* src = x + ((size_t)((b*112 + hs)*112 + wsrc))*128 + g*32;
      #pragma unroll
      for (int j = 0; j < 8; j++){
        f32x4 v4 = *(const f32x4*)(src + 4*j);
        vals[4*j+0]=v4[0]; vals[4*j+1]=v4[1]; vals[4*j+2]=v4[2]; vals[4*j+3]=v4[3];
        sum += v4[0] + v4[1] + v4[2] + v4[3];
        sq  += v4[0]*v4[0] + v4[1]*v4[1] + v4[2]*v4[2] + v4[3]*v4[3];
      }
    } else {
      #pragma unroll
      for (int j = 0; j < 32; j++) vals[j] = 0.f;
    }
    sum += __shfl_xor(sum, 1); sum += __shfl_xor(sum, 2);
    sq  += __shfl_xor(sq, 1);  sq  += __shfl_xor(sq, 2);
    const float mu = sum * (1.f/128.f);
    const float var = sq * (1.f/128.f) - mu*mu;
    const float rs = rsqrtf(var + 1e-5f);
    #pragma unroll
    for (int j = 0; j < 32; j++){
      const int ch = g*32 + j;
      float xn = 0.f;
      if (t < 49) xn = (vals[j] - mu) * rs * ln1w[ch] + ln1b[ch];
      const u16 h = f2bf(xn);
      xw[(t*128 + ch) ^ ((t & 7) << 3)] = h;
      if (j & 1) xnp[j >> 1] |= ((u32)h << 16);
      else       xnp[j >> 1]  = (u32)h;
    }
  }
  __syncthreads();

  // ---- Stage 2: QKV GEMM [64x128]@[128x384] -> qB/kB/pool-vT ----
  {
    const f32x4 fz = {0.f,0.f,0.f,0.f};
    f32x4 acc[4][6];
    #pragma unroll
    for (int mt = 0; mt < 4; mt++)
      #pragma unroll
      for (int nt = 0; nt < 6; nt++) acc[mt][nt] = fz;

    const int col0 = wv * 96;
    #pragma unroll
    for (int kk = 0; kk < 4; kk++){
      const int k0 = kk*32 + (lq << 3);
      bf16x8 a[4];
      #pragma unroll
      for (int mt = 0; mt < 4; mt++){
        const int row = mt*16 + l15;
        a[mt] = ld8s(&xw[(row*128 + k0) ^ ((row & 7) << 3)]);
      }
      #pragma unroll
      for (int nt = 0; nt < 6; nt++){
        const int o = col0 + nt*16 + l15;
        const bf16x8 bb = *(const bf16x8*)(qkvwT + o*128 + k0);
        #pragma unroll
        for (int mt = 0; mt < 4; mt++)
          acc[mt][nt] = mfma16(a[mt], bb, acc[mt][nt]);
      }
    }
    __syncthreads();   // all xw reads done before vT overwrites pool
    #pragma unroll
    for (int nt = 0; nt < 6; nt++){
      const int o = col0 + nt*16 + l15;
      const int which = o >> 7;          // 0:q 1:k 2:v
      const int ch = o & 127;
      const float bias = qkv_b[o];
      #pragma unroll
      for (int mt = 0; mt < 4; mt++){
        #pragma unroll
        for (int r = 0; r < 4; r++){
          const int tok = mt*16 + (lq << 2) + r;
          const float v = acc[mt][nt][r] + bias;
          if (which == 0)      qB[tok*136 + ch] = f2bf(v * 0.25f);
          else if (which == 1) kB[tok*136 + ch] = f2bf(v);
          else                 pool[ch*72 + tok] = f2bf(v);
        }
      }
    }
  }
  __syncthreads();

  // ---- Stage 3: MFMA attention, 4-head batches. S^T = mfma(K,Q, biasC);
  //      softmax across lq lanes; P repacked via shfl; PV; ao -> kB cols. ----
  {
    const f32x4 fz = {0.f,0.f,0.f,0.f};
    const int iq = wv*16 + l15;            // this lane's query token
    const float* bC = biasC + cls*32768 + iq;
    #pragma unroll 1
    for (int hb = 0; hb < 2; hb++){
      // --- S for 4 heads (bias+mask preloaded as C-frag) ---
      float p[4][4][4];
      #pragma unroll
      for (int hh = 0; hh < 4; hh++){
        const int h = hb*4 + hh;
        const bf16x8 bq = (lq < 2) ? ld8s(&qB[iq*136 + h*16 + (lq << 3)]) : bzero();
        const float* bh = bC + h*4096;
        #pragma unroll
        for (int nt = 0; nt < 4; nt++){
          const int keyb = nt*16 + (lq << 2);
          f32x4 cf;
          cf[0] = bh[(keyb+0)*64];
          cf[1] = bh[(keyb+1)*64];
          cf[2] = bh[(keyb+2)*64];
          cf[3] = bh[(keyb+3)*64];
          const bf16x8 ak = (lq < 2) ? ld8s(&kB[(nt*16 + l15)*136 + h*16 + (lq << 3)]) : bzero();
          const f32x4 s4 = mfma16(ak, bq, cf);   // D[key][query] + bias + mask
          #pragma unroll
          for (int r = 0; r < 4; r++) p[hh][nt][r] = s4[r];
        }
      }
      // --- softmax, 4 independent chains ---
      #pragma unroll
      for (int hh = 0; hh < 4; hh++){
        float m = -3e38f;
        #pragma unroll
        for (int nt = 0; nt < 4; nt++)
          #pragma unroll
          for (int r = 0; r < 4; r++) m = fmaxf(m, p[hh][nt][r]);
        m = fmaxf(m, __shfl_xor(m, 16));
        m = fmaxf(m, __shfl_xor(m, 32));
        float sum = 0.f;
        #pragma unroll
        for (int nt = 0; nt < 4; nt++)
          #pragma unroll
          for (int r = 0; r < 4; r++){
            const float e = __expf(p[hh][nt][r] - m);
            p[hh][nt][r] = e;
            sum += e;
          }
        sum += __shfl_xor(sum, 16);
        sum += __shfl_xor(sum, 32);
        const float inv = 1.f / sum;
        #pragma unroll
        for (int nt = 0; nt < 4; nt++)
          #pragma unroll
          for (int r = 0; r < 4; r++) p[hh][nt][r] *= inv;
      }
      // --- repack + PV per head -> oaccb (registers) ---
      f32x4 oaccb[4];
      #pragma unroll
      for (int hh = 0; hh < 4; hh++){
        const int h = hb*4 + hh;
        bf16x8 pa[2];
        #pragma unroll
        for (int kk = 0; kk < 2; kk++){
          us8 tmp;
          #pragma unroll
          for (int j = 0; j < 8; j++){
            const int srcLane = ((((lq << 1) + (j >> 2)) & 3) << 4) + l15;
            const float va = __shfl(p[hh][2*kk    ][j & 3], srcLane);
            const float vb = __shfl(p[hh][2*kk + 1][j & 3], srcLane);
            tmp[j] = f2bf((lq & 2) ? vb : va);
          }
          pa[kk] = __builtin_bit_cast(bf16x8, tmp);
        }
        f32x4 oacc = fz;
        #pragma unroll
        for (int kk = 0; kk < 2; kk++){
          const bf16x8 bv = ld8s(&pool[(h*16 + l15)*72 + kk*32 + (lq << 3)]);
          oacc = mfma16(pa[kk], bv, oacc);
        }
        oaccb[hh] = oacc;
      }
      // --- all waves done reading this batch's kB cols -> overwrite with ao ---
      __syncthreads();
      #pragma unroll
      for (int hh = 0; hh < 4; hh++){
        const int h = hb*4 + hh;
        #pragma unroll
        for (int r = 0; r < 4; r++){
          const int tok = wv*16 + (lq << 2) + r;
          kB[tok*136 + h*16 + l15] = f2bf(oaccb[hh][r]);
        }
      }
    }
  }
  __syncthreads();

  // ---- Stage 4: proj [64x128]@[128x128]; stage result in aoS; coalesced
  //      residual write from (t,g) threads using packed xn. ----
  {
    const f32x4 fz = {0.f,0.f,0.f,0.f};
    f32x4 acc[4][2];
    #pragma unroll
    for (int mt = 0; mt < 4; mt++){ acc[mt][0] = fz; acc[mt][1] = fz; }
    #pragma unroll
    for (int kk = 0; kk < 4; kk++){
      const int k0 = kk*32 + (lq << 3);
      bf16x8 a[4];
      #pragma unroll
      for (int mt = 0; mt < 4; mt++){
        const int row = mt*16 + l15;
        a[mt] = ld8s(&kB[row*136 + k0]);
      }
      #pragma unroll
      for (int nt = 0; nt < 2; nt++){
        const int o = wv*32 + nt*16 + l15;
        const bf16x8 bb = *(const bf16x8*)(projwT + o*128 + k0);
        #pragma unroll
        for (int mt = 0; mt < 4; mt++)
          acc[mt][nt] = mfma16(a[mt], bb, acc[mt][nt]);
      }
    }
    __syncthreads();   // all kB reads done before aoS overlay write
    #pragma unroll
    for (int nt = 0; nt < 2; nt++){
      const int ch = wv*32 + nt*16 + l15;
      const float pb = proj_b[ch];
      #pragma unroll
      for (int mt = 0; mt < 4; mt++){
        #pragma unroll
        for (int r = 0; r < 4; r++){
          const int tok = mt*16 + (lq << 2) + r;
          aoS[(tok*128 + ch) ^ ((tok & 7) << 2)] = acc[mt][nt][r] + pb;
        }
      }
    }
  }
  __syncthreads();

  // ---- Final: y = xn(packed regs) + aoS, coalesced full-row writes ----
  if (t < 49){
    const int rr = t / 7, cc = t % 7;
    const int hs   = (wh*7 + rr + 3) % 112;
    const int wsrc = (ww*7 + cc + 3) % 112;
    float* dst = y + ((size_t)((b*112 + hs)*112 + wsrc))*128 + g*32;
    #pragma unroll
    for (int j = 0; j < 8; j++){
      const int idx = (t*128 + g*32 + 4*j) ^ ((t & 7) << 2);
      const f32x4 a4 = *(const f32x4*)(aoS + idx);
      f32x4 o4;
      #pragma unroll
      for (int e = 0; e < 4; e++){
        const int c = 4*j + e;
        const u16 h = (u16)(xnp[c >> 1] >> ((c & 1) * 16));
        o4[e] = bf2f(h) + a4[e];
      }
      *(f32x4*)(dst + 4*j) = o4;
    }
  }
}

// ---------------------------------------------------------------------------
// Kernel 2: MLP, persistent blocks (grid 768 = 3/CU), grid-stride over
// 64-token tiles -> 8x fewer weight re-reads. In-place on y.
// ---------------------------------------------------------------------------
__global__ __launch_bounds__(256, 3) void mlp_kernel(
    const float* __restrict__ ln2w, const float* __restrict__ ln2b,
    const float* __restrict__ b1, const float* __restrict__ b2,
    const u16* __restrict__ w1T, const u16* __restrict__ w2T,
    float* __restrict__ y)
{
  __shared__ u16 yn[64*128];     // 16KB
  __shared__ u16 hid[64*256];    // 32KB (bf16 hid half; f32 out-stage at end)
  const int tid = threadIdx.x;
  const int lane = tid & 63;
  const int wv = tid >> 6;
  const int l15 = lane & 15;
  const int lq  = lane >> 4;
  const f32x4 fz = {0.f,0.f,0.f,0.f};
  const int t = tid >> 2, g = tid & 3;
  float* hidf = (float*)hid;

  for (int tile = blockIdx.x; tile < 6272; tile += 768){
    const size_t base = (size_t)tile * 64;

    // LN2 -> yn ; y kept in registers (vals)
    float vals[32];
    {
      const float* src = y + (base + t)*128 + g*32;
      float sum = 0.f, sq = 0.f;
      #pragma unroll
      for (int j = 0; j < 8; j++){
        f32x4 v4 = *(const f32x4*)(src + 4*j);
        vals[4*j+0]=v4[0]; vals[4*j+1]=v4[1]; vals[4*j+2]=v4[2]; vals[4*j+3]=v4[3];
        sum += v4[0] + v4[1] + v4[2] + v4[3];
        sq  += v4[0]*v4[0] + v4[1]*v4[1] + v4[2]*v4[2] + v4[3]*v4[3];
      }
      sum += __shfl_xor(sum, 1); sum += __shfl_xor(sum, 2);
      sq  += __shfl_xor(sq, 1);  sq  += __shfl_xor(sq, 2);
      const float mu = sum * (1.f/128.f);
      const float rs = rsqrtf(sq * (1.f/128.f) - mu*mu + 1e-5f);
      #pragma unroll
      for (int j = 0; j < 32; j++){
        const int ch = g*32 + j;
        yn[(t*128 + ch) ^ ((t & 7) << 3)] = f2bf((vals[j] - mu) * rs * ln2w[ch] + ln2b[ch]);
      }
    }
    __syncthreads();

    f32x4 acc2[4][2];
    #pragma unroll
    for (int mt = 0; mt < 4; mt++){ acc2[mt][0] = fz; acc2[mt][1] = fz; }

    #pragma unroll 1
    for (int half = 0; half < 2; half++){
      // GEMM1 [64x128]@[128x256] + GELU -> hid
      {
        f32x4 acc[4][4];
        #pragma unroll
        for (int mt = 0; mt < 4; mt++)
          #pragma unroll
          for (int nt = 0; nt < 4; nt++) acc[mt][nt] = fz;
        #pragma unroll
        for (int kk = 0; kk < 4; kk++){
          const int k0 = kk*32 + (lq << 3);
          bf16x8 a[4];
          #pragma unroll
          for (int mt = 0; mt < 4; mt++){
            const int row = mt*16 + l15;
            a[mt] = ld8s(&yn[(row*128 + k0) ^ ((row & 7) << 3)]);
          }
          #pragma unroll
          for (int nt = 0; nt < 4; nt++){
            const int o = half*256 + wv*64 + nt*16 + l15;
            const bf16x8 bb = *(const bf16x8*)(w1T + o*128 + k0);
            #pragma unroll
            for (int mt = 0; mt < 4; mt++)
              acc[mt][nt] = mfma16(a[mt], bb, acc[mt][nt]);
          }
        }
        if (half == 1) __syncthreads();   // half0's GEMM2 reads done before overwrite
        #pragma unroll
        for (int nt = 0; nt < 4; nt++){
          const int o = half*256 + wv*64 + nt*16 + l15;
          const int cl = o - half*256;           // local col 0..255
          const float bb1 = b1[o];
          #pragma unroll
          for (int mt = 0; mt < 4; mt++){
            #pragma unroll
            for (int r = 0; r < 4; r++){
              const int tok = mt*16 + (lq << 2) + r;
              const float v = acc[mt][nt][r] + bb1;
              const float u = 0.7978845608028654f * (v + 0.044715f * v*v*v);
              const float th = 1.f - 2.f / (__expf(2.f*u) + 1.f);
              const float gel = 0.5f * v * (1.f + th);
              hid[(tok*256 + cl) ^ ((tok & 7) << 3)] = f2bf(gel);
            }
          }
        }
      }
      __syncthreads();

      // GEMM2 partial: [64x256]@[256x128], accumulate acc2
      {
        #pragma unroll
        for (int kk = 0; kk < 8; kk++){
          const int k0 = kk*32 + (lq << 3);      // local k in half: 0..255
          bf16x8 a[4];
          #pragma unroll
          for (int mt = 0; mt < 4; mt++){
            const int row = mt*16 + l15;
            a[mt] = ld8s(&hid[(row*256 + k0) ^ ((row & 7) << 3)]);
          }
          #pragma unroll
          for (int nt = 0; nt < 2; nt++){
            const int o = wv*32 + nt*16 + l15;
            const int kg = half*256 + k0;
            const bf16x8 bb = *(const bf16x8*)(w2T + o*512 + kg);
            #pragma unroll
            for (int mt = 0; mt < 4; mt++)
              acc2[mt][nt] = mfma16(a[mt], bb, acc2[mt][nt]);
          }
        }
      }
    }
    __syncthreads();   // last GEMM2 hid reads done

    // epilogue: stage acc2(+b2) into hid reinterpreted as f32 [64][128]
    {
      #pragma unroll
      for (int nt = 0; nt < 2; nt++){
        const int ch = wv*32 + nt*16 + l15;
        const float bb2 = b2[ch];
        #pragma unroll
        for (int mt = 0; mt < 4; mt++){
          #pragma unroll
          for (int r = 0; r < 4; r++){
            const int tok = mt*16 + (lq << 2) + r;
            hidf[(tok*128 + ch) ^ ((tok & 7) << 2)] = acc2[mt][nt][r] + bb2;
          }
        }
      }
    }
    __syncthreads();

    // residual add in LDS: (t,g) thread owns (t, g*32..+31)
    {
      #pragma unroll
      for (int j = 0; j < 32; j++){
        const int idx = (t*128 + g*32 + j) ^ ((t & 7) << 2);
        hidf[idx] += vals[j];
      }
    }
    __syncthreads();

    // flat fully-contiguous writeback: each wave-instruction stores 1KB
    {
      #pragma unroll
      for (int it = 0; it < 8; it++){
        const int flat = it*1024 + tid*4;
        const int tok = flat >> 7;
        const f32x4 v = *(const f32x4*)(hidf + (flat ^ ((tok & 7) << 2)));
        *(f32x4*)(y + base*128 + flat) = v;
      }
    }
    __syncthreads();   // writeback done before next tile's LDS overwrite
  }
}

// ---------------------------------------------------------------------------
extern "C" void kernel_launch(void* const* d_in, const int* in_sizes, int n_in,
                              void* d_out, int out_size, void* d_ws, size_t ws_size,
                              hipStream_t stream)
{
  const float* x      = (const float*)d_in[0];
  const float* qkv_w  = (const float*)d_in[1];
  const float* qkv_b  = (const float*)d_in[2];
  const float* proj_w = (const float*)d_in[3];
  const float* proj_b = (const float*)d_in[4];
  const float* rpb    = (const float*)d_in[5];
  const float* ln1w   = (const float*)d_in[6];
  const float* ln1b   = (const float*)d_in[7];
  const float* ln2w   = (const float*)d_in[8];
  const float* ln2b   = (const float*)d_in[9];
  const float* w1     = (const float*)d_in[10];
  const float* b1     = (const float*)d_in[11];
  const float* w2     = (const float*)d_in[12];
  const float* b2     = (const float*)d_in[13];

  char* ws = (char*)d_ws;
  u16*   qkvwT  = (u16*)(ws + 0);        // 384*128*2  = 98304
  u16*   projwT = (u16*)(ws + 98304);    // 128*128*2  = 32768   -> 131072
  u16*   w1T    = (u16*)(ws + 131072);   // 512*128*2  = 131072  -> 262144
  u16*   w2T    = (u16*)(ws + 262144);   // 128*512*2  = 131072  -> 393216
  float* biasC  = (float*)(ws + 393216); // 4*8*64*64*4 = 524288 -> 917504
  float* y = (float*)d_out;

  prep_kernel<<<512, 256, 0, stream>>>(qkv_w, proj_w, w1, w2, rpb,
                                       qkvwT, projwT, w1T, w2T, biasC);
  attn_kernel<<<8192, 256, 0, stream>>>(x, ln1w, ln1b, qkv_b, proj_b,
                                        qkvwT, projwT, biasC, y);
  mlp_kernel<<<768, 256, 0, stream>>>(ln2w, ln2b, b1, b2, w1T, w2T, y);
}

// Round 11
// 1278.346 us; speedup vs baseline: 1.7105x; 1.3304x over previous
//
#include <hip/hip_runtime.h>
#include <hip/hip_bf16.h>

#define DI __device__ __forceinline__

typedef unsigned short u16;
typedef unsigned int   u32;
typedef float  f32x4  __attribute__((ext_vector_type(4)));
typedef __bf16 bf16x8 __attribute__((ext_vector_type(8)));
typedef u16    us8    __attribute__((ext_vector_type(8)));

DI u16 f2bf(float f){
  u32 u = __builtin_bit_cast(u32, f);
  u = (u + 0x7fffu + ((u >> 16) & 1u)) >> 16;
  return (u16)u;
}
DI float bf2f(u16 h){
  u32 u = ((u32)h) << 16;
  return __builtin_bit_cast(float, u);
}

DI f32x4 mfma16(bf16x8 a, bf16x8 b, f32x4 c){
  return __builtin_amdgcn_mfma_f32_16x16x32_bf16(a, b, c, 0, 0, 0);
}
DI bf16x8 bzero(){
  us8 z = {0,0,0,0,0,0,0,0};
  return __builtin_bit_cast(bf16x8, z);
}
DI bf16x8 ld8s(const u16* p){ return *(const bf16x8*)p; }

// ---------------------------------------------------------------------------
// Kernel 0: weight prep — bf16 transposed copies + 4 class-fused bias+mask
//           tables biasC[cls][h][key64][query64] (f32, padding baked in).
// ---------------------------------------------------------------------------
__global__ void prep_kernel(const float* __restrict__ qkv_w, const float* __restrict__ proj_w,
                            const float* __restrict__ w1,    const float* __restrict__ w2,
                            const float* __restrict__ rpb,
                            u16* __restrict__ qkvwT, u16* __restrict__ projwT,
                            u16* __restrict__ w1T,   u16* __restrict__ w2T,
                            float* __restrict__ biasC)
{
  const int idx = blockIdx.x * blockDim.x + threadIdx.x;
  const int stride = gridDim.x * blockDim.x;
  for (int i = idx; i < 384*128; i += stride){ int o = i >> 7, k = i & 127; qkvwT[i] = f2bf(qkv_w[k*384 + o]); }
  for (int i = idx; i < 128*128; i += stride){ int o = i >> 7, k = i & 127; projwT[i] = f2bf(proj_w[k*128 + o]); }
  for (int i = idx; i < 512*128; i += stride){ int o = i >> 7, k = i & 127; w1T[i] = f2bf(w1[k*512 + o]); }
  for (int i = idx; i < 128*512; i += stride){ int o = i >> 9, k = i & 511; w2T[i] = f2bf(w2[k*128 + o]); }
  // biasC[cls*32768 + h*4096 + key*64 + query]
  for (int i = idx; i < 4*8*64*64; i += stride){
    const int cls = i >> 15;
    const int rem = i & 32767;
    const int h = rem >> 12;
    const int km = rem & 4095;
    const int key = km >> 6, q = km & 63;
    float v;
    if (key >= 49) v = -1e30f;
    else if (q >= 49) v = 0.f;
    else {
      const int rel = (q/7 - key/7 + 6)*13 + (q%7 - key%7 + 6);
      v = rpb[rel*8 + h];
      const int rhF = cls >> 1, rwF = cls & 1;
      const int labq = (rhF ? ((q/7)   < 4 ? 1 : 2) : 0)*3 + (rwF ? ((q%7)   < 4 ? 1 : 2) : 0);
      const int labk = (rhF ? ((key/7) < 4 ? 1 : 2) : 0)*3 + (rwF ? ((key%7) < 4 ? 1 : 2) : 0);
      if (labq != labk) v -= 100.f;
    }
    biasC[i] = v;
  }
}

// ---------------------------------------------------------------------------
// Kernel 1: one block = one 7x7 window. LN1 + shift-gather + QKV(MFMA) +
//           MFMA attention (S^T trick, bias+mask as MFMA C-input, P in regs,
//           4-head batches) + proj + residual (coalesced via LDS stage).
//           (unchanged from round 10)
// ---------------------------------------------------------------------------
__global__ __launch_bounds__(256, 3) void attn_kernel(
    const float* __restrict__ x,
    const float* __restrict__ ln1w, const float* __restrict__ ln1b,
    const float* __restrict__ qkv_b, const float* __restrict__ proj_b,
    const u16* __restrict__ qkvwT, const u16* __restrict__ projwT,
    const float* __restrict__ biasC,
    float* __restrict__ y)
{
  __shared__ u16 qkPool[2*64*136]; // qB | kB ; stage-4 overlay: aoS f32[64*128]
  __shared__ u16 pool[128*72];     // phase A: xn bf16 [64][128] swz; phase B: vT stride 72

  u16* qB = qkPool;
  u16* kB = qkPool + 64*136;
  u16* xw = pool;
  float* aoS = (float*)qkPool;

  const int tid = threadIdx.x;
  const int lane = tid & 63;
  const int wv = tid >> 6;       // wave 0..3
  const int l15 = lane & 15;
  const int lq  = lane >> 4;     // 0..3
  const int blk = blockIdx.x;
  const int b  = blk >> 8;
  const int wi = blk & 255;
  const int wh = wi >> 4, ww = wi & 15;
  const int cls = ((wh == 15) ? 2 : 0) + ((ww == 15) ? 1 : 0);
  const int t = tid >> 2, g = tid & 3;   // token / channel-quarter roles

  u32 xnp[16];                   // xn (bf16 pairs) for (t, g*32..g*32+31)

  // ---- Stage 1: gather (roll -3,-3) + LN1 -> xw (bf16, swizzled) + xnp ----
  {
    float vals[32];
    float sum = 0.f, sq = 0.f;
    if (t < 49){
      const int r = t / 7, c = t % 7;
      const int hs   = (wh*7 + r + 3) % 112;
      const int wsrc = (ww*7 + c + 3) % 112;
      const float* src = x + ((size_t)((b*112 + hs)*112 + wsrc))*128 + g*32;
      #pragma unroll
      for (int j = 0; j < 8; j++){
        f32x4 v4 = *(const f32x4*)(src + 4*j);
        vals[4*j+0]=v4[0]; vals[4*j+1]=v4[1]; vals[4*j+2]=v4[2]; vals[4*j+3]=v4[3];
        sum += v4[0] + v4[1] + v4[2] + v4[3];
        sq  += v4[0]*v4[0] + v4[1]*v4[1] + v4[2]*v4[2] + v4[3]*v4[3];
      }
    } else {
      #pragma unroll
      for (int j = 0; j < 32; j++) vals[j] = 0.f;
    }
    sum += __shfl_xor(sum, 1); sum += __shfl_xor(sum, 2);
    sq  += __shfl_xor(sq, 1);  sq  += __shfl_xor(sq, 2);
    const float mu = sum * (1.f/128.f);
    const float var = sq * (1.f/128.f) - mu*mu;
    const float rs = rsqrtf(var + 1e-5f);
    #pragma unroll
    for (int j = 0; j < 32; j++){
      const int ch = g*32 + j;
      float xn = 0.f;
      if (t < 49) xn = (vals[j] - mu) * rs * ln1w[ch] + ln1b[ch];
      const u16 h = f2bf(xn);
      xw[(t*128 + ch) ^ ((t & 7) << 3)] = h;
      if (j & 1) xnp[j >> 1] |= ((u32)h << 16);
      else       xnp[j >> 1]  = (u32)h;
    }
  }
  __syncthreads();

  // ---- Stage 2: QKV GEMM [64x128]@[128x384] -> qB/kB/pool-vT ----
  {
    const f32x4 fz = {0.f,0.f,0.f,0.f};
    f32x4 acc[4][6];
    #pragma unroll
    for (int mt = 0; mt < 4; mt++)
      #pragma unroll
      for (int nt = 0; nt < 6; nt++) acc[mt][nt] = fz;

    const int col0 = wv * 96;
    #pragma unroll
    for (int kk = 0; kk < 4; kk++){
      const int k0 = kk*32 + (lq << 3);
      bf16x8 a[4];
      #pragma unroll
      for (int mt = 0; mt < 4; mt++){
        const int row = mt*16 + l15;
        a[mt] = ld8s(&xw[(row*128 + k0) ^ ((row & 7) << 3)]);
      }
      #pragma unroll
      for (int nt = 0; nt < 6; nt++){
        const int o = col0 + nt*16 + l15;
        const bf16x8 bb = *(const bf16x8*)(qkvwT + o*128 + k0);
        #pragma unroll
        for (int mt = 0; mt < 4; mt++)
          acc[mt][nt] = mfma16(a[mt], bb, acc[mt][nt]);
      }
    }
    __syncthreads();   // all xw reads done before vT overwrites pool
    #pragma unroll
    for (int nt = 0; nt < 6; nt++){
      const int o = col0 + nt*16 + l15;
      const int which = o >> 7;          // 0:q 1:k 2:v
      const int ch = o & 127;
      const float bias = qkv_b[o];
      #pragma unroll
      for (int mt = 0; mt < 4; mt++){
        #pragma unroll
        for (int r = 0; r < 4; r++){
          const int tok = mt*16 + (lq << 2) + r;
          const float v = acc[mt][nt][r] + bias;
          if (which == 0)      qB[tok*136 + ch] = f2bf(v * 0.25f);
          else if (which == 1) kB[tok*136 + ch] = f2bf(v);
          else                 pool[ch*72 + tok] = f2bf(v);
        }
      }
    }
  }
  __syncthreads();

  // ---- Stage 3: MFMA attention, 4-head batches. S^T = mfma(K,Q, biasC);
  //      softmax across lq lanes; P repacked via shfl; PV; ao -> kB cols. ----
  {
    const f32x4 fz = {0.f,0.f,0.f,0.f};
    const int iq = wv*16 + l15;            // this lane's query token
    const float* bC = biasC + cls*32768 + iq;
    #pragma unroll 1
    for (int hb = 0; hb < 2; hb++){
      // --- S for 4 heads (bias+mask preloaded as C-frag) ---
      float p[4][4][4];
      #pragma unroll
      for (int hh = 0; hh < 4; hh++){
        const int h = hb*4 + hh;
        const bf16x8 bq = (lq < 2) ? ld8s(&qB[iq*136 + h*16 + (lq << 3)]) : bzero();
        const float* bh = bC + h*4096;
        #pragma unroll
        for (int nt = 0; nt < 4; nt++){
          const int keyb = nt*16 + (lq << 2);
          f32x4 cf;
          cf[0] = bh[(keyb+0)*64];
          cf[1] = bh[(keyb+1)*64];
          cf[2] = bh[(keyb+2)*64];
          cf[3] = bh[(keyb+3)*64];
          const bf16x8 ak = (lq < 2) ? ld8s(&kB[(nt*16 + l15)*136 + h*16 + (lq << 3)]) : bzero();
          const f32x4 s4 = mfma16(ak, bq, cf);   // D[key][query] + bias + mask
          #pragma unroll
          for (int r = 0; r < 4; r++) p[hh][nt][r] = s4[r];
        }
      }
      // --- softmax, 4 independent chains ---
      #pragma unroll
      for (int hh = 0; hh < 4; hh++){
        float m = -3e38f;
        #pragma unroll
        for (int nt = 0; nt < 4; nt++)
          #pragma unroll
          for (int r = 0; r < 4; r++) m = fmaxf(m, p[hh][nt][r]);
        m = fmaxf(m, __shfl_xor(m, 16));
        m = fmaxf(m, __shfl_xor(m, 32));
        float sum = 0.f;
        #pragma unroll
        for (int nt = 0; nt < 4; nt++)
          #pragma unroll
          for (int r = 0; r < 4; r++){
            const float e = __expf(p[hh][nt][r] - m);
            p[hh][nt][r] = e;
            sum += e;
          }
        sum += __shfl_xor(sum, 16);
        sum += __shfl_xor(sum, 32);
        const float inv = 1.f / sum;
        #pragma unroll
        for (int nt = 0; nt < 4; nt++)
          #pragma unroll
          for (int r = 0; r < 4; r++) p[hh][nt][r] *= inv;
      }
      // --- repack + PV per head -> oaccb (registers) ---
      f32x4 oaccb[4];
      #pragma unroll
      for (int hh = 0; hh < 4; hh++){
        const int h = hb*4 + hh;
        bf16x8 pa[2];
        #pragma unroll
        for (int kk = 0; kk < 2; kk++){
          us8 tmp;
          #pragma unroll
          for (int j = 0; j < 8; j++){
            const int srcLane = ((((lq << 1) + (j >> 2)) & 3) << 4) + l15;
            const float va = __shfl(p[hh][2*kk    ][j & 3], srcLane);
            const float vb = __shfl(p[hh][2*kk + 1][j & 3], srcLane);
            tmp[j] = f2bf((lq & 2) ? vb : va);
          }
          pa[kk] = __builtin_bit_cast(bf16x8, tmp);
        }
        f32x4 oacc = fz;
        #pragma unroll
        for (int kk = 0; kk < 2; kk++){
          const bf16x8 bv = ld8s(&pool[(h*16 + l15)*72 + kk*32 + (lq << 3)]);
          oacc = mfma16(pa[kk], bv, oacc);
        }
        oaccb[hh] = oacc;
      }
      // --- all waves done reading this batch's kB cols -> overwrite with ao ---
      __syncthreads();
      #pragma unroll
      for (int hh = 0; hh < 4; hh++){
        const int h = hb*4 + hh;
        #pragma unroll
        for (int r = 0; r < 4; r++){
          const int tok = wv*16 + (lq << 2) + r;
          kB[tok*136 + h*16 + l15] = f2bf(oaccb[hh][r]);
        }
      }
    }
  }
  __syncthreads();

  // ---- Stage 4: proj [64x128]@[128x128]; stage result in aoS; coalesced
  //      residual write from (t,g) threads using packed xn. ----
  {
    const f32x4 fz = {0.f,0.f,0.f,0.f};
    f32x4 acc[4][2];
    #pragma unroll
    for (int mt = 0; mt < 4; mt++){ acc[mt][0] = fz; acc[mt][1] = fz; }
    #pragma unroll
    for (int kk = 0; kk < 4; kk++){
      const int k0 = kk*32 + (lq << 3);
      bf16x8 a[4];
      #pragma unroll
      for (int mt = 0; mt < 4; mt++){
        const int row = mt*16 + l15;
        a[mt] = ld8s(&kB[row*136 + k0]);
      }
      #pragma unroll
      for (int nt = 0; nt < 2; nt++){
        const int o = wv*32 + nt*16 + l15;
        const bf16x8 bb = *(const bf16x8*)(projwT + o*128 + k0);
        #pragma unroll
        for (int mt = 0; mt < 4; mt++)
          acc[mt][nt] = mfma16(a[mt], bb, acc[mt][nt]);
      }
    }
    __syncthreads();   // all kB reads done before aoS overlay write
    #pragma unroll
    for (int nt = 0; nt < 2; nt++){
      const int ch = wv*32 + nt*16 + l15;
      const float pb = proj_b[ch];
      #pragma unroll
      for (int mt = 0; mt < 4; mt++){
        #pragma unroll
        for (int r = 0; r < 4; r++){
          const int tok = mt*16 + (lq << 2) + r;
          aoS[(tok*128 + ch) ^ ((tok & 7) << 2)] = acc[mt][nt][r] + pb;
        }
      }
    }
  }
  __syncthreads();

  // ---- Final: y = xn(packed regs) + aoS, coalesced full-row writes ----
  if (t < 49){
    const int rr = t / 7, cc = t % 7;
    const int hs   = (wh*7 + rr + 3) % 112;
    const int wsrc = (ww*7 + cc + 3) % 112;
    float* dst = y + ((size_t)((b*112 + hs)*112 + wsrc))*128 + g*32;
    #pragma unroll
    for (int j = 0; j < 8; j++){
      const int idx = (t*128 + g*32 + 4*j) ^ ((t & 7) << 2);
      const f32x4 a4 = *(const f32x4*)(aoS + idx);
      f32x4 o4;
      #pragma unroll
      for (int e = 0; e < 4; e++){
        const int c = 4*j + e;
        const u16 h = (u16)(xnp[c >> 1] >> ((c & 1) * 16));
        o4[e] = bf2f(h) + a4[e];
      }
      *(f32x4*)(dst + 4*j) = o4;
    }
  }
}

// ---------------------------------------------------------------------------
// Kernel 2: MLP, M=128 token tiles (grid 3136), hidden in four 128-col
// passes -> each weight fragment feeds 8 M-tiles (2x weight amortization,
// 64KB per-pass footprint). LDS 64KB -> 2 blocks/CU. In-place RMW epilogue.
// ---------------------------------------------------------------------------
__global__ __launch_bounds__(256, 2) void mlp_kernel(
    const float* __restrict__ ln2w, const float* __restrict__ ln2b,
    const float* __restrict__ b1, const float* __restrict__ b2,
    const u16* __restrict__ w1T, const u16* __restrict__ w2T,
    float* __restrict__ y)
{
  __shared__ u16 yn[128*128];    // 32KB
  __shared__ u16 hid[128*128];   // 32KB (one 128-col hidden pass)
  const int tid = threadIdx.x;
  const int lane = tid & 63;
  const int wv = tid >> 6;
  const int l15 = lane & 15;
  const int lq  = lane >> 4;
  const size_t base = (size_t)blockIdx.x * 128;
  const f32x4 fz = {0.f,0.f,0.f,0.f};

  // LN2 -> yn : thread handles token t2 = tid>>1, channel half gh = tid&1
  {
    const int t2 = tid >> 1, gh = tid & 1;
    const float* src = y + (base + t2)*128 + gh*64;
    float vals[64];
    float sum = 0.f, sq = 0.f;
    #pragma unroll
    for (int j = 0; j < 16; j++){
      f32x4 v4 = *(const f32x4*)(src + 4*j);
      vals[4*j+0]=v4[0]; vals[4*j+1]=v4[1]; vals[4*j+2]=v4[2]; vals[4*j+3]=v4[3];
      sum += v4[0] + v4[1] + v4[2] + v4[3];
      sq  += v4[0]*v4[0] + v4[1]*v4[1] + v4[2]*v4[2] + v4[3]*v4[3];
    }
    sum += __shfl_xor(sum, 1);
    sq  += __shfl_xor(sq, 1);
    const float mu = sum * (1.f/128.f);
    const float rs = rsqrtf(sq * (1.f/128.f) - mu*mu + 1e-5f);
    #pragma unroll
    for (int j = 0; j < 64; j++){
      const int ch = gh*64 + j;
      yn[(t2*128 + ch) ^ ((t2 & 7) << 3)] = f2bf((vals[j] - mu) * rs * ln2w[ch] + ln2b[ch]);
    }
  }
  __syncthreads();

  f32x4 acc2[8][2];
  #pragma unroll
  for (int mt = 0; mt < 8; mt++){ acc2[mt][0] = fz; acc2[mt][1] = fz; }

  #pragma unroll 1
  for (int pass = 0; pass < 4; pass++){
    // GEMM1 [128x128]@[128x128] + GELU -> hid (cols pass*128..+127)
    {
      f32x4 acc[8][2];
      #pragma unroll
      for (int mt = 0; mt < 8; mt++){ acc[mt][0] = fz; acc[mt][1] = fz; }
      #pragma unroll
      for (int kk = 0; kk < 4; kk++){
        const int k0 = kk*32 + (lq << 3);
        bf16x8 a[8];
        #pragma unroll
        for (int mt = 0; mt < 8; mt++){
          const int row = mt*16 + l15;
          a[mt] = ld8s(&yn[(row*128 + k0) ^ ((row & 7) << 3)]);
        }
        #pragma unroll
        for (int nt = 0; nt < 2; nt++){
          const int o = pass*128 + wv*32 + nt*16 + l15;
          const bf16x8 bb = *(const bf16x8*)(w1T + o*128 + k0);
          #pragma unroll
          for (int mt = 0; mt < 8; mt++)
            acc[mt][nt] = mfma16(a[mt], bb, acc[mt][nt]);
        }
      }
      if (pass > 0) __syncthreads();   // prev pass's GEMM2 hid reads done
      #pragma unroll
      for (int nt = 0; nt < 2; nt++){
        const int o = pass*128 + wv*32 + nt*16 + l15;
        const int cl = wv*32 + nt*16 + l15;    // local col 0..127
        const float bb1 = b1[o];
        #pragma unroll
        for (int mt = 0; mt < 8; mt++){
          #pragma unroll
          for (int r = 0; r < 4; r++){
            const int tok = mt*16 + (lq << 2) + r;
            const float v = acc[mt][nt][r] + bb1;
            const float u = 0.7978845608028654f * (v + 0.044715f * v*v*v);
            const float th = 1.f - 2.f / (__expf(2.f*u) + 1.f);
            const float gel = 0.5f * v * (1.f + th);
            hid[(tok*128 + cl) ^ ((tok & 7) << 3)] = f2bf(gel);
          }
        }
      }
    }
    __syncthreads();

    // GEMM2 partial: [128x128]@[128x128], accumulate acc2
    {
      #pragma unroll
      for (int kk = 0; kk < 4; kk++){
        const int k0 = kk*32 + (lq << 3);      // local k in pass: 0..127
        bf16x8 a[8];
        #pragma unroll
        for (int mt = 0; mt < 8; mt++){
          const int row = mt*16 + l15;
          a[mt] = ld8s(&hid[(row*128 + k0) ^ ((row & 7) << 3)]);
        }
        #pragma unroll
        for (int nt = 0; nt < 2; nt++){
          const int o = wv*32 + nt*16 + l15;
          const int kg = pass*128 + k0;
          const bf16x8 bb = *(const bf16x8*)(w2T + o*512 + kg);
          #pragma unroll
          for (int mt = 0; mt < 8; mt++)
            acc2[mt][nt] = mfma16(a[mt], bb, acc2[mt][nt]);
        }
      }
    }
  }

  // epilogue: out = y + hid, in place (RMW)
  #pragma unroll
  for (int nt = 0; nt < 2; nt++){
    const int ch = wv*32 + nt*16 + l15;
    const float bb2 = b2[ch];
    #pragma unroll
    for (int mt = 0; mt < 8; mt++){
      #pragma unroll
      for (int r = 0; r < 4; r++){
        const int tok = mt*16 + (lq << 2) + r;
        const size_t gi = (base + tok)*128 + ch;
        y[gi] = y[gi] + acc2[mt][nt][r] + bb2;
      }
    }
  }
}

// ---------------------------------------------------------------------------
extern "C" void kernel_launch(void* const* d_in, const int* in_sizes, int n_in,
                              void* d_out, int out_size, void* d_ws, size_t ws_size,
                              hipStream_t stream)
{
  const float* x      = (const float*)d_in[0];
  const float* qkv_w  = (const float*)d_in[1];
  const float* qkv_b  = (const float*)d_in[2];
  const float* proj_w = (const float*)d_in[3];
  const float* proj_b = (const float*)d_in[4];
  const float* rpb    = (const float*)d_in[5];
  const float* ln1w   = (const float*)d_in[6];
  const float* ln1b   = (const float*)d_in[7];
  const float* ln2w   = (const float*)d_in[8];
  const float* ln2b   = (const float*)d_in[9];
  const float* w1     = (const float*)d_in[10];
  const float* b1     = (const float*)d_in[11];
  const float* w2     = (const float*)d_in[12];
  const float* b2     = (const float*)d_in[13];

  char* ws = (char*)d_ws;
  u16*   qkvwT  = (u16*)(ws + 0);        // 384*128*2  = 98304
  u16*   projwT = (u16*)(ws + 98304);    // 128*128*2  = 32768   -> 131072
  u16*   w1T    = (u16*)(ws + 131072);   // 512*128*2  = 131072  -> 262144
  u16*   w2T    = (u16*)(ws + 262144);   // 128*512*2  = 131072  -> 393216
  float* biasC  = (float*)(ws + 393216); // 4*8*64*64*4 = 524288 -> 917504
  float* y = (float*)d_out;

  prep_kernel<<<512, 256, 0, stream>>>(qkv_w, proj_w, w1, w2, rpb,
                                       qkvwT, projwT, w1T, w2T, biasC);
  attn_kernel<<<8192, 256, 0, stream>>>(x, ln1w, ln1b, qkv_b, proj_b,
                                        qkvwT, projwT, biasC, y);
  mlp_kernel<<<3136, 256, 0, stream>>>(ln2w, ln2b, b1, b2, w1T, w2T, y);
}

// Round 12
// 1126.396 us; speedup vs baseline: 1.9412x; 1.1349x over previous
//
#include <hip/hip_runtime.h>
#include <hip/hip_bf16.h>

#define DI __device__ __forceinline__

typedef unsigned short u16;
typedef unsigned int   u32;
typedef float  f32x4  __attribute__((ext_vector_type(4)));
typedef __bf16 bf16x8 __attribute__((ext_vector_type(8)));
typedef u16    us8    __attribute__((ext_vector_type(8)));

DI u16 f2bf(float f){
  u32 u = __builtin_bit_cast(u32, f);
  u = (u + 0x7fffu + ((u >> 16) & 1u)) >> 16;
  return (u16)u;
}
DI float bf2f(u16 h){
  u32 u = ((u32)h) << 16;
  return __builtin_bit_cast(float, u);
}

DI f32x4 mfma16(bf16x8 a, bf16x8 b, f32x4 c){
  return __builtin_amdgcn_mfma_f32_16x16x32_bf16(a, b, c, 0, 0, 0);
}
DI bf16x8 bzero(){
  us8 z = {0,0,0,0,0,0,0,0};
  return __builtin_bit_cast(bf16x8, z);
}
DI bf16x8 ld8s(const u16* p){ return *(const bf16x8*)p; }

// ---------------------------------------------------------------------------
// Kernel 0: weight prep — bf16 transposed copies + 4 class-fused bias+mask
//           tables biasC[cls][h][key64][query64] (f32, padding baked in).
// ---------------------------------------------------------------------------
__global__ void prep_kernel(const float* __restrict__ qkv_w, const float* __restrict__ proj_w,
                            const float* __restrict__ w1,    const float* __restrict__ w2,
                            const float* __restrict__ rpb,
                            u16* __restrict__ qkvwT, u16* __restrict__ projwT,
                            u16* __restrict__ w1T,   u16* __restrict__ w2T,
                            float* __restrict__ biasC)
{
  const int idx = blockIdx.x * blockDim.x + threadIdx.x;
  const int stride = gridDim.x * blockDim.x;
  for (int i = idx; i < 384*128; i += stride){ int o = i >> 7, k = i & 127; qkvwT[i] = f2bf(qkv_w[k*384 + o]); }
  for (int i = idx; i < 128*128; i += stride){ int o = i >> 7, k = i & 127; projwT[i] = f2bf(proj_w[k*128 + o]); }
  for (int i = idx; i < 512*128; i += stride){ int o = i >> 7, k = i & 127; w1T[i] = f2bf(w1[k*512 + o]); }
  for (int i = idx; i < 128*512; i += stride){ int o = i >> 9, k = i & 511; w2T[i] = f2bf(w2[k*128 + o]); }
  // biasC[cls*32768 + h*4096 + key*64 + query]
  for (int i = idx; i < 4*8*64*64; i += stride){
    const int cls = i >> 15;
    const int rem = i & 32767;
    const int h = rem >> 12;
    const int km = rem & 4095;
    const int key = km >> 6, q = km & 63;
    float v;
    if (key >= 49) v = -1e30f;
    else if (q >= 49) v = 0.f;
    else {
      const int rel = (q/7 - key/7 + 6)*13 + (q%7 - key%7 + 6);
      v = rpb[rel*8 + h];
      const int rhF = cls >> 1, rwF = cls & 1;
      const int labq = (rhF ? ((q/7)   < 4 ? 1 : 2) : 0)*3 + (rwF ? ((q%7)   < 4 ? 1 : 2) : 0);
      const int labk = (rhF ? ((key/7) < 4 ? 1 : 2) : 0)*3 + (rwF ? ((key%7) < 4 ? 1 : 2) : 0);
      if (labq != labk) v -= 100.f;
    }
    biasC[i] = v;
  }
}

// ---------------------------------------------------------------------------
// Kernel 1: one block = one 7x7 window. LN1 + shift-gather + QKV(MFMA) +
//           MFMA attention (S^T trick, bias+mask as MFMA C-input, P in regs,
//           4-head batches) + proj + residual (coalesced via LDS stage).
//           (unchanged from round 11)
// ---------------------------------------------------------------------------
__global__ __launch_bounds__(256, 3) void attn_kernel(
    const float* __restrict__ x,
    const float* __restrict__ ln1w, const float* __restrict__ ln1b,
    const float* __restrict__ qkv_b, const float* __restrict__ proj_b,
    const u16* __restrict__ qkvwT, const u16* __restrict__ projwT,
    const float* __restrict__ biasC,
    float* __restrict__ y)
{
  __shared__ u16 qkPool[2*64*136]; // qB | kB ; stage-4 overlay: aoS f32[64*128]
  __shared__ u16 pool[128*72];     // phase A: xn bf16 [64][128] swz; phase B: vT stride 72

  u16* qB = qkPool;
  u16* kB = qkPool + 64*136;
  u16* xw = pool;
  float* aoS = (float*)qkPool;

  const int tid = threadIdx.x;
  const int lane = tid & 63;
  const int wv = tid >> 6;       // wave 0..3
  const int l15 = lane & 15;
  const int lq  = lane >> 4;     // 0..3
  const int blk = blockIdx.x;
  const int b  = blk >> 8;
  const int wi = blk & 255;
  const int wh = wi >> 4, ww = wi & 15;
  const int cls = ((wh == 15) ? 2 : 0) + ((ww == 15) ? 1 : 0);
  const int t = tid >> 2, g = tid & 3;   // token / channel-quarter roles

  u32 xnp[16];                   // xn (bf16 pairs) for (t, g*32..g*32+31)

  // ---- Stage 1: gather (roll -3,-3) + LN1 -> xw (bf16, swizzled) + xnp ----
  {
    float vals[32];
    float sum = 0.f, sq = 0.f;
    if (t < 49){
      const int r = t / 7, c = t % 7;
      const int hs   = (wh*7 + r + 3) % 112;
      const int wsrc = (ww*7 + c + 3) % 112;
      const float* src = x + ((size_t)((b*112 + hs)*112 + wsrc))*128 + g*32;
      #pragma unroll
      for (int j = 0; j < 8; j++){
        f32x4 v4 = *(const f32x4*)(src + 4*j);
        vals[4*j+0]=v4[0]; vals[4*j+1]=v4[1]; vals[4*j+2]=v4[2]; vals[4*j+3]=v4[3];
        sum += v4[0] + v4[1] + v4[2] + v4[3];
        sq  += v4[0]*v4[0] + v4[1]*v4[1] + v4[2]*v4[2] + v4[3]*v4[3];
      }
    } else {
      #pragma unroll
      for (int j = 0; j < 32; j++) vals[j] = 0.f;
    }
    sum += __shfl_xor(sum, 1); sum += __shfl_xor(sum, 2);
    sq  += __shfl_xor(sq, 1);  sq  += __shfl_xor(sq, 2);
    const float mu = sum * (1.f/128.f);
    const float var = sq * (1.f/128.f) - mu*mu;
    const float rs = rsqrtf(var + 1e-5f);
    #pragma unroll
    for (int j = 0; j < 32; j++){
      const int ch = g*32 + j;
      float xn = 0.f;
      if (t < 49) xn = (vals[j] - mu) * rs * ln1w[ch] + ln1b[ch];
      const u16 h = f2bf(xn);
      xw[(t*128 + ch) ^ ((t & 7) << 3)] = h;
      if (j & 1) xnp[j >> 1] |= ((u32)h << 16);
      else       xnp[j >> 1]  = (u32)h;
    }
  }
  __syncthreads();

  // ---- Stage 2: QKV GEMM [64x128]@[128x384] -> qB/kB/pool-vT ----
  {
    const f32x4 fz = {0.f,0.f,0.f,0.f};
    f32x4 acc[4][6];
    #pragma unroll
    for (int mt = 0; mt < 4; mt++)
      #pragma unroll
      for (int nt = 0; nt < 6; nt++) acc[mt][nt] = fz;

    const int col0 = wv * 96;
    #pragma unroll
    for (int kk = 0; kk < 4; kk++){
      const int k0 = kk*32 + (lq << 3);
      bf16x8 a[4];
      #pragma unroll
      for (int mt = 0; mt < 4; mt++){
        const int row = mt*16 + l15;
        a[mt] = ld8s(&xw[(row*128 + k0) ^ ((row & 7) << 3)]);
      }
      #pragma unroll
      for (int nt = 0; nt < 6; nt++){
        const int o = col0 + nt*16 + l15;
        const bf16x8 bb = *(const bf16x8*)(qkvwT + o*128 + k0);
        #pragma unroll
        for (int mt = 0; mt < 4; mt++)
          acc[mt][nt] = mfma16(a[mt], bb, acc[mt][nt]);
      }
    }
    __syncthreads();   // all xw reads done before vT overwrites pool
    #pragma unroll
    for (int nt = 0; nt < 6; nt++){
      const int o = col0 + nt*16 + l15;
      const int which = o >> 7;          // 0:q 1:k 2:v
      const int ch = o & 127;
      const float bias = qkv_b[o];
      #pragma unroll
      for (int mt = 0; mt < 4; mt++){
        #pragma unroll
        for (int r = 0; r < 4; r++){
          const int tok = mt*16 + (lq << 2) + r;
          const float v = acc[mt][nt][r] + bias;
          if (which == 0)      qB[tok*136 + ch] = f2bf(v * 0.25f);
          else if (which == 1) kB[tok*136 + ch] = f2bf(v);
          else                 pool[ch*72 + tok] = f2bf(v);
        }
      }
    }
  }
  __syncthreads();

  // ---- Stage 3: MFMA attention, 4-head batches. S^T = mfma(K,Q, biasC);
  //      softmax across lq lanes; P repacked via shfl; PV; ao -> kB cols. ----
  {
    const f32x4 fz = {0.f,0.f,0.f,0.f};
    const int iq = wv*16 + l15;            // this lane's query token
    const float* bC = biasC + cls*32768 + iq;
    #pragma unroll 1
    for (int hb = 0; hb < 2; hb++){
      // --- S for 4 heads (bias+mask preloaded as C-frag) ---
      float p[4][4][4];
      #pragma unroll
      for (int hh = 0; hh < 4; hh++){
        const int h = hb*4 + hh;
        const bf16x8 bq = (lq < 2) ? ld8s(&qB[iq*136 + h*16 + (lq << 3)]) : bzero();
        const float* bh = bC + h*4096;
        #pragma unroll
        for (int nt = 0; nt < 4; nt++){
          const int keyb = nt*16 + (lq << 2);
          f32x4 cf;
          cf[0] = bh[(keyb+0)*64];
          cf[1] = bh[(keyb+1)*64];
          cf[2] = bh[(keyb+2)*64];
          cf[3] = bh[(keyb+3)*64];
          const bf16x8 ak = (lq < 2) ? ld8s(&kB[(nt*16 + l15)*136 + h*16 + (lq << 3)]) : bzero();
          const f32x4 s4 = mfma16(ak, bq, cf);   // D[key][query] + bias + mask
          #pragma unroll
          for (int r = 0; r < 4; r++) p[hh][nt][r] = s4[r];
        }
      }
      // --- softmax, 4 independent chains ---
      #pragma unroll
      for (int hh = 0; hh < 4; hh++){
        float m = -3e38f;
        #pragma unroll
        for (int nt = 0; nt < 4; nt++)
          #pragma unroll
          for (int r = 0; r < 4; r++) m = fmaxf(m, p[hh][nt][r]);
        m = fmaxf(m, __shfl_xor(m, 16));
        m = fmaxf(m, __shfl_xor(m, 32));
        float sum = 0.f;
        #pragma unroll
        for (int nt = 0; nt < 4; nt++)
          #pragma unroll
          for (int r = 0; r < 4; r++){
            const float e = __expf(p[hh][nt][r] - m);
            p[hh][nt][r] = e;
            sum += e;
          }
        sum += __shfl_xor(sum, 16);
        sum += __shfl_xor(sum, 32);
        const float inv = 1.f / sum;
        #pragma unroll
        for (int nt = 0; nt < 4; nt++)
          #pragma unroll
          for (int r = 0; r < 4; r++) p[hh][nt][r] *= inv;
      }
      // --- repack + PV per head -> oaccb (registers) ---
      f32x4 oaccb[4];
      #pragma unroll
      for (int hh = 0; hh < 4; hh++){
        const int h = hb*4 + hh;
        bf16x8 pa[2];
        #pragma unroll
        for (int kk = 0; kk < 2; kk++){
          us8 tmp;
          #pragma unroll
          for (int j = 0; j < 8; j++){
            const int srcLane = ((((lq << 1) + (j >> 2)) & 3) << 4) + l15;
            const float va = __shfl(p[hh][2*kk    ][j & 3], srcLane);
            const float vb = __shfl(p[hh][2*kk + 1][j & 3], srcLane);
            tmp[j] = f2bf((lq & 2) ? vb : va);
          }
          pa[kk] = __builtin_bit_cast(bf16x8, tmp);
        }
        f32x4 oacc = fz;
        #pragma unroll
        for (int kk = 0; kk < 2; kk++){
          const bf16x8 bv = ld8s(&pool[(h*16 + l15)*72 + kk*32 + (lq << 3)]);
          oacc = mfma16(pa[kk], bv, oacc);
        }
        oaccb[hh] = oacc;
      }
      // --- all waves done reading this batch's kB cols -> overwrite with ao ---
      __syncthreads();
      #pragma unroll
      for (int hh = 0; hh < 4; hh++){
        const int h = hb*4 + hh;
        #pragma unroll
        for (int r = 0; r < 4; r++){
          const int tok = wv*16 + (lq << 2) + r;
          kB[tok*136 + h*16 + l15] = f2bf(oaccb[hh][r]);
        }
      }
    }
  }
  __syncthreads();

  // ---- Stage 4: proj [64x128]@[128x128]; stage result in aoS; coalesced
  //      residual write from (t,g) threads using packed xn. ----
  {
    const f32x4 fz = {0.f,0.f,0.f,0.f};
    f32x4 acc[4][2];
    #pragma unroll
    for (int mt = 0; mt < 4; mt++){ acc[mt][0] = fz; acc[mt][1] = fz; }
    #pragma unroll
    for (int kk = 0; kk < 4; kk++){
      const int k0 = kk*32 + (lq << 3);
      bf16x8 a[4];
      #pragma unroll
      for (int mt = 0; mt < 4; mt++){
        const int row = mt*16 + l15;
        a[mt] = ld8s(&kB[row*136 + k0]);
      }
      #pragma unroll
      for (int nt = 0; nt < 2; nt++){
        const int o = wv*32 + nt*16 + l15;
        const bf16x8 bb = *(const bf16x8*)(projwT + o*128 + k0);
        #pragma unroll
        for (int mt = 0; mt < 4; mt++)
          acc[mt][nt] = mfma16(a[mt], bb, acc[mt][nt]);
      }
    }
    __syncthreads();   // all kB reads done before aoS overlay write
    #pragma unroll
    for (int nt = 0; nt < 2; nt++){
      const int ch = wv*32 + nt*16 + l15;
      const float pb = proj_b[ch];
      #pragma unroll
      for (int mt = 0; mt < 4; mt++){
        #pragma unroll
        for (int r = 0; r < 4; r++){
          const int tok = mt*16 + (lq << 2) + r;
          aoS[(tok*128 + ch) ^ ((tok & 7) << 2)] = acc[mt][nt][r] + pb;
        }
      }
    }
  }
  __syncthreads();

  // ---- Final: y = xn(packed regs) + aoS, coalesced full-row writes ----
  if (t < 49){
    const int rr = t / 7, cc = t % 7;
    const int hs   = (wh*7 + rr + 3) % 112;
    const int wsrc = (ww*7 + cc + 3) % 112;
    float* dst = y + ((size_t)((b*112 + hs)*112 + wsrc))*128 + g*32;
    #pragma unroll
    for (int j = 0; j < 8; j++){
      const int idx = (t*128 + g*32 + 4*j) ^ ((t & 7) << 2);
      const f32x4 a4 = *(const f32x4*)(aoS + idx);
      f32x4 o4;
      #pragma unroll
      for (int e = 0; e < 4; e++){
        const int c = 4*j + e;
        const u16 h = (u16)(xnp[c >> 1] >> ((c & 1) * 16));
        o4[e] = bf2f(h) + a4[e];
      }
      *(f32x4*)(dst + 4*j) = o4;
    }
  }
}

// ---------------------------------------------------------------------------
// Kernel 2: MLP, M=128 token tiles (grid 3136), hidden in four 128-col
// passes. Weight B-fragments batch-preloaded ahead of each MFMA phase so
// global-load latency is off the MFMA critical path. 2 blk/CU, RMW epilogue.
// ---------------------------------------------------------------------------
__global__ __launch_bounds__(256, 2) void mlp_kernel(
    const float* __restrict__ ln2w, const float* __restrict__ ln2b,
    const float* __restrict__ b1, const float* __restrict__ b2,
    const u16* __restrict__ w1T, const u16* __restrict__ w2T,
    float* __restrict__ y)
{
  __shared__ u16 yn[128*128];    // 32KB
  __shared__ u16 hid[128*128];   // 32KB (one 128-col hidden pass)
  const int tid = threadIdx.x;
  const int lane = tid & 63;
  const int wv = tid >> 6;
  const int l15 = lane & 15;
  const int lq  = lane >> 4;
  const size_t base = (size_t)blockIdx.x * 128;
  const f32x4 fz = {0.f,0.f,0.f,0.f};

  // LN2 -> yn : thread handles token t2 = tid>>1, channel half gh = tid&1
  {
    const int t2 = tid >> 1, gh = tid & 1;
    const float* src = y + (base + t2)*128 + gh*64;
    float vals[64];
    float sum = 0.f, sq = 0.f;
    #pragma unroll
    for (int j = 0; j < 16; j++){
      f32x4 v4 = *(const f32x4*)(src + 4*j);
      vals[4*j+0]=v4[0]; vals[4*j+1]=v4[1]; vals[4*j+2]=v4[2]; vals[4*j+3]=v4[3];
      sum += v4[0] + v4[1] + v4[2] + v4[3];
      sq  += v4[0]*v4[0] + v4[1]*v4[1] + v4[2]*v4[2] + v4[3]*v4[3];
    }
    sum += __shfl_xor(sum, 1);
    sq  += __shfl_xor(sq, 1);
    const float mu = sum * (1.f/128.f);
    const float rs = rsqrtf(sq * (1.f/128.f) - mu*mu + 1e-5f);
    #pragma unroll
    for (int j = 0; j < 64; j++){
      const int ch = gh*64 + j;
      yn[(t2*128 + ch) ^ ((t2 & 7) << 3)] = f2bf((vals[j] - mu) * rs * ln2w[ch] + ln2b[ch]);
    }
  }
  __syncthreads();

  f32x4 acc2[8][2];
  #pragma unroll
  for (int mt = 0; mt < 8; mt++){ acc2[mt][0] = fz; acc2[mt][1] = fz; }

  #pragma unroll 1
  for (int pass = 0; pass < 4; pass++){
    // --- preload GEMM1 B-fragments (8 loads in flight) ---
    bf16x8 bb1[4][2];
    #pragma unroll
    for (int kk = 0; kk < 4; kk++){
      const int k0 = kk*32 + (lq << 3);
      #pragma unroll
      for (int nt = 0; nt < 2; nt++){
        const int o = pass*128 + wv*32 + nt*16 + l15;
        bb1[kk][nt] = *(const bf16x8*)(w1T + o*128 + k0);
      }
    }
    // GEMM1 [128x128]@[128x128] -> acc
    f32x4 acc[8][2];
    #pragma unroll
    for (int mt = 0; mt < 8; mt++){ acc[mt][0] = fz; acc[mt][1] = fz; }
    #pragma unroll
    for (int kk = 0; kk < 4; kk++){
      const int k0 = kk*32 + (lq << 3);
      bf16x8 a[8];
      #pragma unroll
      for (int mt = 0; mt < 8; mt++){
        const int row = mt*16 + l15;
        a[mt] = ld8s(&yn[(row*128 + k0) ^ ((row & 7) << 3)]);
      }
      #pragma unroll
      for (int nt = 0; nt < 2; nt++)
        #pragma unroll
        for (int mt = 0; mt < 8; mt++)
          acc[mt][nt] = mfma16(a[mt], bb1[kk][nt], acc[mt][nt]);
    }
    // --- preload GEMM2 B-fragments; latency covered by GELU + barrier ---
    bf16x8 bb2[4][2];
    #pragma unroll
    for (int kk = 0; kk < 4; kk++){
      const int k0 = kk*32 + (lq << 3);
      #pragma unroll
      for (int nt = 0; nt < 2; nt++){
        const int o = wv*32 + nt*16 + l15;
        bb2[kk][nt] = *(const bf16x8*)(w2T + o*512 + pass*128 + k0);
      }
    }
    if (pass > 0) __syncthreads();   // prev pass's GEMM2 hid reads done
    // GELU -> hid
    #pragma unroll
    for (int nt = 0; nt < 2; nt++){
      const int o = pass*128 + wv*32 + nt*16 + l15;
      const int cl = wv*32 + nt*16 + l15;    // local col 0..127
      const float bb1s = b1[o];
      #pragma unroll
      for (int mt = 0; mt < 8; mt++){
        #pragma unroll
        for (int r = 0; r < 4; r++){
          const int tok = mt*16 + (lq << 2) + r;
          const float v = acc[mt][nt][r] + bb1s;
          const float u = 0.7978845608028654f * (v + 0.044715f * v*v*v);
          const float th = 1.f - 2.f / (__expf(2.f*u) + 1.f);
          const float gel = 0.5f * v * (1.f + th);
          hid[(tok*128 + cl) ^ ((tok & 7) << 3)] = f2bf(gel);
        }
      }
    }
    __syncthreads();

    // GEMM2 partial: [128x128]@[128x128], accumulate acc2
    #pragma unroll
    for (int kk = 0; kk < 4; kk++){
      const int k0 = kk*32 + (lq << 3);      // local k in pass: 0..127
      bf16x8 a[8];
      #pragma unroll
      for (int mt = 0; mt < 8; mt++){
        const int row = mt*16 + l15;
        a[mt] = ld8s(&hid[(row*128 + k0) ^ ((row & 7) << 3)]);
      }
      #pragma unroll
      for (int nt = 0; nt < 2; nt++)
        #pragma unroll
        for (int mt = 0; mt < 8; mt++)
          acc2[mt][nt] = mfma16(a[mt], bb2[kk][nt], acc2[mt][nt]);
    }
  }

  // epilogue: out = y + hid, in place (RMW)
  #pragma unroll
  for (int nt = 0; nt < 2; nt++){
    const int ch = wv*32 + nt*16 + l15;
    const float bb2s = b2[ch];
    #pragma unroll
    for (int mt = 0; mt < 8; mt++){
      #pragma unroll
      for (int r = 0; r < 4; r++){
        const int tok = mt*16 + (lq << 2) + r;
        const size_t gi = (base + tok)*128 + ch;
        y[gi] = y[gi] + acc2[mt][nt][r] + bb2s;
      }
    }
  }
}

// ---------------------------------------------------------------------------
extern "C" void kernel_launch(void* const* d_in, const int* in_sizes, int n_in,
                              void* d_out, int out_size, void* d_ws, size_t ws_size,
                              hipStream_t stream)
{
  const float* x      = (const float*)d_in[0];
  const float* qkv_w  = (const float*)d_in[1];
  const float* qkv_b  = (const float*)d_in[2];
  const float* proj_w = (const float*)d_in[3];
  const float* proj_b = (const float*)d_in[4];
  const float* rpb    = (const float*)d_in[5];
  const float* ln1w   = (const float*)d_in[6];
  const float* ln1b   = (const float*)d_in[7];
  const float* ln2w   = (const float*)d_in[8];
  const float* ln2b   = (const float*)d_in[9];
  const float* w1     = (const float*)d_in[10];
  const float* b1     = (const float*)d_in[11];
  const float* w2     = (const float*)d_in[12];
  const float* b2     = (const float*)d_in[13];

  char* ws = (char*)d_ws;
  u16*   qkvwT  = (u16*)(ws + 0);        // 384*128*2  = 98304
  u16*   projwT = (u16*)(ws + 98304);    // 128*128*2  = 32768   -> 131072
  u16*   w1T    = (u16*)(ws + 131072);   // 512*128*2  = 131072  -> 262144
  u16*   w2T    = (u16*)(ws + 262144);   // 128*512*2  = 131072  -> 393216
  float* biasC  = (float*)(ws + 393216); // 4*8*64*64*4 = 524288 -> 917504
  float* y = (float*)d_out;

  prep_kernel<<<512, 256, 0, stream>>>(qkv_w, proj_w, w1, w2, rpb,
                                       qkvwT, projwT, w1T, w2T, biasC);
  attn_kernel<<<8192, 256, 0, stream>>>(x, ln1w, ln1b, qkv_b, proj_b,
                                        qkvwT, projwT, biasC, y);
  mlp_kernel<<<3136, 256, 0, stream>>>(ln2w, ln2b, b1, b2, w1T, w2T, y);
}